// Round 1
// baseline (2981.615 us; speedup 1.0000x reference)
//
#include <hip/hip_runtime.h>

// ---------------------------------------------------------------------------
// AutoregressiveMatrixChain on MI355X, fp32, multi-kernel baseline.
// Key algebra: pk/pv GEMMs eliminated by transforming queries (q@W_pq@W_pk^T)
// and deferring W_pv to after the PV reduction (w@prompt)@W_pv.
// Flash attention with K=V=prompt, unnormalized exp (scores bounded), split-K
// over 64 wave-chunks; small GEMMs use k-split partial sums (KSg slices).
// ---------------------------------------------------------------------------

#define DINL __device__ __forceinline__

enum { A_RAW = 0, A_PSUM = 1, A_PSRAW = 2, A_FLASH = 3, A_TANHMS = 4 };

struct SG {
  const float* Bm;   // weight [K][N] (or [N][K] if bt)
  const float* Bg;   // extra single column (gate) for n >= Ncore
  const float* a0;   // A source 0
  const float* a1;   // A source 1 (slotq / codebook)
  const float* a2;   // A source 2 (flash l / opmax)
  float* out;        // psums [KSg][M][ldo]
  float* w0;         // side write (ms)
  float* w1;         // side write (d_out summary)
  int M, K, N, Ncore, KSg, NB, kslice, ksh, lda, ldb, ldo, MA, P, amode, bt, mr;
  float scale;
};

DINL float dot4(float4 a, float4 b) {
  return fmaf(a.x, b.x, fmaf(a.y, b.y, fmaf(a.z, b.z, a.w * b.w)));
}
DINL unsigned sortable(float f) {
  unsigned u = __float_as_uint(f);
  return (u & 0x80000000u) ? ~u : (u | 0x80000000u);
}
#define AXPY4(A, W, P) \
  { A.x = fmaf(W, P.x, A.x); A.y = fmaf(W, P.y, A.y); A.z = fmaf(W, P.z, A.z); A.w = fmaf(W, P.w, A.w); }

// ---------------------------------------------------------------------------
// small GEMM body: C_psum[ks][m][n] = A[m, kslice]*B[kslice, n] (*scale)
// A staged in LDS (various source modes), B read from global (or LDS-transposed
// tile when bt=1). grid = KSg*NB blocks, 256 threads.
// ---------------------------------------------------------------------------
template <int MR>
DINL void sgemm_body(const SG p, int bx, char* smem) {
  float* As = (float*)smem;                      // up to 4352 floats
  float* Bs = (float*)(smem + 17408);            // 4160 floats
  float* Rl = (float*)(smem + 17408 + 16640);    // 16 floats
  int* Ridx = (int*)Rl;
  const int t = threadIdx.x;
  const int ks = bx / p.NB, nb = bx % p.NB;
  const int kslice = p.kslice;
  const int kb = ks * kslice;

  if (p.amode == A_FLASH) {
    if (t < 16) {
      float s = 0.f;
      for (int c = 0; c < 64; c++) s += p.a2[c * 16 + t];
      Rl[t] = 1.f / s;
    }
    __syncthreads();
  } else if (p.amode == A_TANHMS) {
    if (t < 16) {
      unsigned long long best = 0ull;
      const unsigned long long* om = (const unsigned long long*)p.a2;
      for (int c = 0; c < 256; c++) {
        unsigned long long v = om[c * 16 + t];
        best = v > best ? v : best;
      }
      Ridx[t] = 8192 - (int)(unsigned)(best & 0xFFFFFFFFull);
    }
    __syncthreads();
  }

  const int tot = p.M * kslice;
  for (int idx = t; idx < tot; idx += 256) {
    const int m = idx >> p.ksh;
    const int kl = idx & (kslice - 1);
    float v = 0.f;
    if (p.amode == A_RAW) {
      v = p.a0[m * p.lda + kb + kl];
    } else if (p.amode == A_PSUM) {
      for (int s = 0; s < p.P; s++) v += p.a0[(s * p.MA + m) * p.lda + kb + kl];
    } else if (p.amode == A_PSRAW) {
      if (m < 16) {
        for (int s = 0; s < p.P; s++) v += p.a0[(s * p.MA + m) * p.lda + kb + kl];
      } else {
        v = p.a1[(m - 16) * 1024 + kb + kl];
      }
    } else if (p.amode == A_FLASH) {
      for (int c = 0; c < 64; c++) v += p.a0[((c * 16 + m) << 10) + kb + kl];
      v *= Rl[m];
    } else {  // A_TANHMS: ms = tanh(codebook[idx] + sum(k8p))
      float s = 0.f;
      for (int si = 0; si < 8; si++) s += p.a0[((si * 16 + m) << 10) + kb + kl];
      s = tanhf(s + p.a1[(Ridx[m] << 10) + kb + kl]);
      if (nb == 0) {
        p.w0[(m << 10) + kb + kl] = s;   // ms
        p.w1[(m << 12) + kb + kl] = s;   // d_out summary (w1 pre-offset by it*1024)
      }
      v = s;
    }
    As[(m << p.ksh) + kl] = v;
  }
  __syncthreads();

  const int nl = t & 63, mg = t >> 6;
  const int n = nb * 64 + nl;
  const bool nok = (n < p.N);
  float acc[MR];
#pragma unroll
  for (int i = 0; i < MR; i++) acc[i] = 0.f;

  if (!p.bt) {
    const bool useg = nok && (n >= p.Ncore);
    const float* Bc = p.Bm + n;
    for (int k4 = 0; k4 < kslice; k4 += 4) {
      float bv[4];
#pragma unroll
      for (int u = 0; u < 4; u++) {
        bv[u] = 0.f;
        if (nok) bv[u] = useg ? p.Bg[kb + k4 + u] : Bc[(kb + k4 + u) * p.ldb];
      }
#pragma unroll
      for (int i = 0; i < MR; i++) {
        const int m = mg + 4 * i;
        if (MR == 4 || m < p.M) {
          const float4 av = *(const float4*)&As[(m << p.ksh) + k4];
          acc[i] = fmaf(av.x, bv[0], acc[i]);
          acc[i] = fmaf(av.y, bv[1], acc[i]);
          acc[i] = fmaf(av.z, bv[2], acc[i]);
          acc[i] = fmaf(av.w, bv[3], acc[i]);
        }
      }
    }
  } else {
    // B is [N][K]; stage 64x64 tiles transposed into LDS
    for (int kt = 0; kt < kslice; kt += 64) {
      __syncthreads();
      for (int idx = t; idx < 4096; idx += 256) {
        const int i2 = idx >> 6, j2 = idx & 63;
        Bs[j2 * 65 + i2] = p.Bm[(nb * 64 + i2) * p.ldb + kb + kt + j2];
      }
      __syncthreads();
      for (int k4 = 0; k4 < 64; k4 += 4) {
        float bv[4];
#pragma unroll
        for (int u = 0; u < 4; u++) bv[u] = Bs[(k4 + u) * 65 + nl];
#pragma unroll
        for (int i = 0; i < MR; i++) {
          const int m = mg + 4 * i;
          if (MR == 4 || m < p.M) {
            const float4 av = *(const float4*)&As[(m << p.ksh) + kt + k4];
            acc[i] = fmaf(av.x, bv[0], acc[i]);
            acc[i] = fmaf(av.y, bv[1], acc[i]);
            acc[i] = fmaf(av.z, bv[2], acc[i]);
            acc[i] = fmaf(av.w, bv[3], acc[i]);
          }
        }
      }
    }
  }

  if (nok) {
#pragma unroll
    for (int i = 0; i < MR; i++) {
      const int m = mg + 4 * i;
      if (MR == 4 || m < p.M) p.out[(ks * p.M + m) * p.ldo + n] = acc[i] * p.scale;
    }
  }
}

__global__ __launch_bounds__(256) void k_sgemm(SG p) {
  __shared__ __align__(16) char smem[34176];
  if (p.mr == 4) sgemm_body<4>(p, blockIdx.x, smem);
  else sgemm_body<7>(p, blockIdx.x, smem);
}

__global__ __launch_bounds__(256) void k_sgemm2(SG p1, SG p2, int split) {
  __shared__ __align__(16) char smem[34176];
  const int bx = blockIdx.x;
  const SG& p = (bx < split) ? p1 : p2;
  const int b2 = (bx < split) ? bx : bx - split;
  if (p.mr == 4) sgemm_body<4>(p, b2, smem);
  else sgemm_body<7>(p, b2, smem);
}

// ---------------------------------------------------------------------------
// fused: [K6b sgemm (blocks 0..127)] + [codebook argmax (blocks 128..383)]
// codebook part: scores[b][c] = 2*op_pre[b].cb[c] - |cb[c]|^2, packed-u64 max.
// ---------------------------------------------------------------------------
__global__ __launch_bounds__(256) void k_gemm_cb(SG p, const float* __restrict__ opp,
                                                 const float* __restrict__ cbv,
                                                 const float* __restrict__ cbsqv,
                                                 unsigned long long* __restrict__ opmaxp) {
  __shared__ __align__(16) char smem[65536];
  const int bx = blockIdx.x;
  if (bx < 128) {
    sgemm_body<7>(p, bx, smem);
    return;
  }
  const int bx2 = bx - 128;
  const int t = threadIdx.x;
  // stage op_pre[16][1024] (sum of 8 psums) into swizzled LDS
  for (int idx = t; idx < 16384; idx += 256) {
    const int m = idx >> 10, h = idx & 1023;
    float s = 0.f;
    for (int si = 0; si < 8; si++) s += opp[((si * 16 + m) << 10) + h];
    const int x = (m << 12) + (h << 2);
    *(float*)(smem + (x ^ (((x >> 7) & 7) << 4))) = s;
  }
  __syncthreads();
  const int w = t >> 6, l = t & 63;
  const int bxl = 64 * l;
  const int key = ((bxl >> 7) & 7) << 4;
  const int o0 = bxl ^ key, o1 = (bxl + 16) ^ key, o2 = (bxl + 32) ^ key, o3 = (bxl + 48) ^ key;
  unsigned long long bk[16];
#pragma unroll
  for (int m = 0; m < 16; m++) bk[m] = 0ull;
  const int cbase = (bx2 << 5) + (w << 3);
  for (int ci = 0; ci < 8; ci++) {
    const int c = cbase + ci;
    const float4* cr = (const float4*)(cbv + (c << 10));
    const float4 c0 = cr[4 * l], c1 = cr[4 * l + 1], c2 = cr[4 * l + 2], c3 = cr[4 * l + 3];
    float sm[16];
#pragma unroll
    for (int m = 0; m < 16; m++) {
      const char* qp = smem + (m << 12);
      const float4 a0 = *(const float4*)(qp + o0);
      const float4 a1 = *(const float4*)(qp + o1);
      const float4 a2 = *(const float4*)(qp + o2);
      const float4 a3 = *(const float4*)(qp + o3);
      sm[m] = dot4(a0, c0) + dot4(a1, c1) + dot4(a2, c2) + dot4(a3, c3);
    }
#pragma unroll
    for (int off = 32; off > 0; off >>= 1) {
#pragma unroll
      for (int m = 0; m < 16; m++) sm[m] += __shfl_xor(sm[m], off);
    }
    const float cq = cbsqv[c];
#pragma unroll
    for (int m = 0; m < 16; m++) {
      const float sc = fmaf(2.f, sm[m], -cq);
      const unsigned long long k2 = ((unsigned long long)sortable(sc) << 32) | (unsigned)(8192 - c);
      bk[m] = k2 > bk[m] ? k2 : bk[m];
    }
  }
  __syncthreads();
  unsigned long long* red = (unsigned long long*)smem;
  if (l == 0) {
#pragma unroll
    for (int m = 0; m < 16; m++) red[w * 16 + m] = bk[m];
  }
  __syncthreads();
  if (t < 16) {
    unsigned long long b2 = red[t];
    for (int ww = 1; ww < 4; ww++) {
      const unsigned long long v = red[ww * 16 + t];
      b2 = v > b2 ? v : b2;
    }
    opmaxp[bx2 * 16 + t] = b2;
  }
}

// ---------------------------------------------------------------------------
// flash attention, state pass: Q=1 per batch. grid (16 chunkblk, 16 b), 256thr.
// each wave owns 32 keys; unnormalized exp; outputs acc[chunk][b][1024], l.
// ---------------------------------------------------------------------------
__global__ __launch_bounds__(256) void k_flash_state(const float* __restrict__ prompt,
                                                     const float* __restrict__ qs2,
                                                     float* __restrict__ accst,
                                                     float* __restrict__ lst) {
  const int b = blockIdx.y;
  const int w = threadIdx.x >> 6, l = threadIdx.x & 63;
  const int chunk = blockIdx.x * 4 + w;
  float4 q[4];
#pragma unroll
  for (int r = 0; r < 4; r++) q[r] = make_float4(0.f, 0.f, 0.f, 0.f);
#pragma unroll
  for (int s = 0; s < 8; s++) {
    const float4* qp = (const float4*)(qs2 + ((s * 16 + b) << 10) + 16 * l);
#pragma unroll
    for (int r = 0; r < 4; r++) {
      const float4 v = qp[r];
      q[r].x += v.x; q[r].y += v.y; q[r].z += v.z; q[r].w += v.w;
    }
  }
  float4 acc[4];
#pragma unroll
  for (int r = 0; r < 4; r++) acc[r] = make_float4(0.f, 0.f, 0.f, 0.f);
  float lsum = 0.f;
  const float* pbase = prompt + ((b * 2048 + chunk * 32) << 10) + 16 * l;
  for (int k = 0; k < 32; k++) {
    const float4* pr = (const float4*)(pbase + (k << 10));
    const float4 p0 = pr[0], p1 = pr[1], p2 = pr[2], p3 = pr[3];
    float s = dot4(q[0], p0) + dot4(q[1], p1) + dot4(q[2], p2) + dot4(q[3], p3);
#pragma unroll
    for (int off = 32; off > 0; off >>= 1) s += __shfl_xor(s, off);
    const float wgt = __expf(s);
    lsum += wgt;
    AXPY4(acc[0], wgt, p0); AXPY4(acc[1], wgt, p1);
    AXPY4(acc[2], wgt, p2); AXPY4(acc[3], wgt, p3);
  }
  float* ob = accst + ((chunk * 16 + b) << 10) + 16 * l;
#pragma unroll
  for (int r = 0; r < 4; r++) ((float4*)ob)[r] = acc[r];
  if (l == 0) lst[chunk * 16 + b] = lsum;
}

// ---------------------------------------------------------------------------
// flash attention, slot pass: Q=9 per batch (q = base[b] + slotrow[j]).
// q staged in LDS with XOR swizzle (b128-read bank-conflict fix).
// ---------------------------------------------------------------------------
__global__ __launch_bounds__(256, 2) void k_flash_slot(const float* __restrict__ prompt,
                                                       const float* __restrict__ qb2,
                                                       float* __restrict__ accsl,
                                                       float* __restrict__ lsl) {
  __shared__ __align__(16) char qsm[40960];
  char* qrows = qsm;
  float* qbase = (float*)(qsm + 36864);
  const int b = blockIdx.y;
  const int t = threadIdx.x;
  for (int idx = t; idx < 1024; idx += 256) {
    float s = 0.f;
    for (int si = 0; si < 8; si++) s += qb2[((si * 25 + b) << 10) + idx];
    qbase[idx] = s;
  }
  __syncthreads();
  for (int idx = t; idx < 9216; idx += 256) {
    const int j = idx >> 10, h = idx & 1023;
    float s = qbase[h];
    for (int si = 0; si < 8; si++) s += qb2[((si * 25 + 16 + j) << 10) + h];
    const int x = (j << 12) + (h << 2);
    *(float*)(qrows + (x ^ (((x >> 7) & 7) << 4))) = s;
  }
  __syncthreads();
  const int w = t >> 6, l = t & 63;
  const int chunk = blockIdx.x * 4 + w;
  const int bxl = 64 * l;
  const int key = ((bxl >> 7) & 7) << 4;
  const int o0 = bxl ^ key, o1 = (bxl + 16) ^ key, o2 = (bxl + 32) ^ key, o3 = (bxl + 48) ^ key;
  float4 acc[9][4];
  float lsum[9];
#pragma unroll
  for (int j = 0; j < 9; j++) {
    lsum[j] = 0.f;
#pragma unroll
    for (int r = 0; r < 4; r++) acc[j][r] = make_float4(0.f, 0.f, 0.f, 0.f);
  }
  const float* pbase = prompt + ((b * 2048 + chunk * 32) << 10) + 16 * l;
  for (int k = 0; k < 32; k++) {
    const float4* pr = (const float4*)(pbase + (k << 10));
    const float4 p0 = pr[0], p1 = pr[1], p2 = pr[2], p3 = pr[3];
    float sj[9];
#pragma unroll
    for (int j = 0; j < 9; j++) {
      const char* qp = qrows + (j << 12);
      const float4 a0 = *(const float4*)(qp + o0);
      const float4 a1 = *(const float4*)(qp + o1);
      const float4 a2 = *(const float4*)(qp + o2);
      const float4 a3 = *(const float4*)(qp + o3);
      sj[j] = dot4(a0, p0) + dot4(a1, p1) + dot4(a2, p2) + dot4(a3, p3);
    }
#pragma unroll
    for (int off = 32; off > 0; off >>= 1) {
#pragma unroll
      for (int j = 0; j < 9; j++) sj[j] += __shfl_xor(sj[j], off);
    }
#pragma unroll
    for (int j = 0; j < 9; j++) {
      const float wgt = __expf(sj[j]);
      lsum[j] += wgt;
      AXPY4(acc[j][0], wgt, p0); AXPY4(acc[j][1], wgt, p1);
      AXPY4(acc[j][2], wgt, p2); AXPY4(acc[j][3], wgt, p3);
    }
  }
  float* ob = accsl + (((chunk * 16 + b) * 9) << 10) + 16 * l;
#pragma unroll
  for (int j = 0; j < 9; j++) {
    float4* o4 = (float4*)(ob + (j << 10));
    o4[0] = acc[j][0]; o4[1] = acc[j][1]; o4[2] = acc[j][2]; o4[3] = acc[j][3];
  }
  if (l == 0) {
#pragma unroll
    for (int j = 0; j < 9; j++) lsl[(chunk * 16 + b) * 9 + j] = lsum[j];
  }
}

// ---------------------------------------------------------------------------
// K7: combine slot flash partials, gates + mask (+global fallback), masked mean
// grid 64 blocks (4 per batch), 256 threads, thread = one h element.
// ---------------------------------------------------------------------------
__global__ __launch_bounds__(256) void k_k7(const float* __restrict__ accsl,
                                            const float* __restrict__ lsl,
                                            const float* __restrict__ qb1,
                                            const float* __restrict__ bgate,
                                            float* __restrict__ ssum) {
  __shared__ float rl[9];
  __shared__ float gpre[25];
  __shared__ int mask_s[9];
  __shared__ float cntInv;
  const int bx = blockIdx.x;
  const int b = bx >> 2;
  const int t = threadIdx.x;
  if (t < 9) {
    float s = 0.f;
    for (int c = 0; c < 64; c++) s += lsl[(c * 16 + b) * 9 + t];
    rl[t] = 1.f / s;
  }
  if (t >= 32 && t < 57) {
    const int m = t - 32;
    float s = 0.f;
    for (int si = 0; si < 8; si++) s += qb1[(si * 25 + m) * 1025 + 1024];
    gpre[m] = s;
  }
  __syncthreads();
  if (t == 0) {
    const float bg = bgate[0];
    bool any = false;
    for (int bb = 0; bb < 16; bb++)
      for (int j = 0; j < 9; j++)
        if (gpre[bb] + gpre[16 + j] + bg >= 0.f) any = true;
    int cnt = 0;
    if (any) {
      for (int j = 0; j < 9; j++) {
        const int s = (gpre[b] + gpre[16 + j] + bg >= 0.f) ? 1 : 0;
        mask_s[j] = s;
        cnt += s;
      }
    } else {
      float bv = -3.4e38f;
      int bj = 0;
      for (int j = 0; j < 9; j++) {
        const float v = gpre[b] + gpre[16 + j] + bg;
        if (v > bv) { bv = v; bj = j; }
      }
      for (int j = 0; j < 9; j++) mask_s[j] = (j == bj) ? 1 : 0;
      cnt = 1;
    }
    cntInv = 1.f / (float)(cnt > 0 ? cnt : 1);
  }
  __syncthreads();
  const int h = ((bx & 3) << 8) + t;
  float v = 0.f;
  for (int j = 0; j < 9; j++) {
    if (mask_s[j]) {
      float s = 0.f;
      for (int c = 0; c < 64; c++) s += accsl[(((c * 16 + b) * 9 + j) << 10) + h];
      v = fmaf(s, rl[j], v);
    }
  }
  ssum[(b << 10) + h] = v * cntInv;
}

// ---------------------------------------------------------------------------
// K9b: GRU elementwise finish (blocks 0..63) + stop logits (blocks 64..67)
// ---------------------------------------------------------------------------
__global__ __launch_bounds__(256) void k_k9b(const float* __restrict__ gp,
                                             const float* __restrict__ bih,
                                             const float* __restrict__ bhh,
                                             float* __restrict__ state,
                                             const float* __restrict__ stctx,
                                             const float* __restrict__ ms,
                                             const float* __restrict__ Wstop,
                                             const float* __restrict__ bstop,
                                             float* __restrict__ dout, int it) {
  const int bx = blockIdx.x;
  const int t = threadIdx.x;
  if (bx < 64) {
    const int gi = bx * 256 + t;
    const int b = gi >> 10, h = gi & 1023;
    float ir = 0.f, iz = 0.f, inn = 0.f, hr = 0.f, hz = 0.f, hn = 0.f;
    for (int s = 0; s < 4; s++) {
      const float* g = gp + (s * 16 + b) * 6144;
      ir += g[h]; iz += g[1024 + h]; inn += g[2048 + h];
      hr += g[3072 + h]; hz += g[4096 + h]; hn += g[5120 + h];
    }
    ir += bih[h]; iz += bih[1024 + h]; inn += bih[2048 + h];
    hr += bhh[h]; hz += bhh[1024 + h]; hn += bhh[2048 + h];
    const float r = 1.f / (1.f + __expf(-(ir + hr)));
    const float z = 1.f / (1.f + __expf(-(iz + hz)));
    const float n = tanhf(fmaf(r, hn, inn));
    const float hold = state[gi];
    state[gi] = (1.f - z) * n + z * hold;
  } else {
    const int wid = (bx - 64) * 4 + (t >> 6);
    const int l = t & 63;
    float p = 0.f;
    for (int i = 0; i < 16; i++) {
      const int h = l + (i << 6);
      float sc = 0.f;
      for (int s = 0; s < 8; s++) sc += stctx[((s * 16 + wid) << 10) + h];
      p = fmaf(sc, Wstop[h], p);
      p = fmaf(ms[(wid << 10) + h], Wstop[1024 + h], p);
    }
#pragma unroll
    for (int off = 32; off > 0; off >>= 1) p += __shfl_xor(p, off);
    if (l == 0) {
      const float lg = p + bstop[0];
      dout[65536 + wid * 4 + it] = lg;
      dout[65600 + wid * 4 + it] = 1.f / (1.f + __expf(-lg));
    }
  }
}

__global__ void k_k10(float* __restrict__ dout) {
  const int t = threadIdx.x;
  if (t < 16) {
    int cl = 4;
    for (int it = 0; it < 4; it++) {
      if (dout[65536 + t * 4 + it] >= 0.f) { cl = it + 1; break; }
    }
    dout[65664 + t] = (float)cl;
  }
}

// --------------------------- setup kernels ---------------------------------
__global__ __launch_bounds__(256) void k_meanpsum(const float* __restrict__ src,
                                                  float* __restrict__ out, int Rtot, int rps) {
  const int bx = blockIdx.x;
  const int s = bx >> 6, b = (bx >> 2) & 15, hb = bx & 3;
  const int h = hb * 256 + threadIdx.x;
  float v = 0.f;
  const int r0 = s * rps;
  for (int r = 0; r < rps; r++) v += src[(b * Rtot + r0 + r) * 1024 + h];
  out[((s * 16 + b) << 10) + h] = v;
}

__global__ __launch_bounds__(256) void k_cbsq(const float* __restrict__ cbv,
                                              float* __restrict__ out) {
  const int c = blockIdx.x * 4 + (threadIdx.x >> 6);
  const int l = threadIdx.x & 63;
  const float4* cr = (const float4*)(cbv + (c << 10));
  float s = 0.f;
#pragma unroll
  for (int r = 0; r < 4; r++) {
    const float4 v = cr[4 * l + r];
    s += dot4(v, v);
  }
#pragma unroll
  for (int off = 32; off > 0; off >>= 1) s += __shfl_xor(s, off);
  if (l == 0) out[c] = s;
}

__global__ __launch_bounds__(256) void k_meancat(const float* __restrict__ pmp,
                                                 const float* __restrict__ lmp,
                                                 float* __restrict__ mean) {
  const int gi = blockIdx.x * 256 + threadIdx.x;
  const int b = gi >> 11, k = gi & 2047;
  float v = 0.f;
  if (k < 1024) {
    for (int s = 0; s < 8; s++) v += pmp[((s * 16 + b) << 10) + k];
    v *= (1.f / 2048.f);
  } else {
    const int kk = k - 1024;
    for (int s = 0; s < 4; s++) v += lmp[((s * 16 + b) << 10) + kk];
    v *= (1.f / 512.f);
  }
  mean[b * 2048 + k] = v;
}

__global__ __launch_bounds__(256) void k_s2b(const float* __restrict__ s2p,
                                             float* __restrict__ state) {
  const int gi = blockIdx.x * 256 + threadIdx.x;
  const int b = gi >> 10, h = gi & 1023;
  float s = 0.f;
  for (int si = 0; si < 8; si++) s += s2p[((si * 16 + b) << 10) + h];
  state[gi] = tanhf(s);
}

// ---------------------------------------------------------------------------
// workspace layout (floats). total ~12.38M floats (~47.2 MB).
// ---------------------------------------------------------------------------
static constexpr int F_PMP   = 0;
static constexpr int F_LMP   = F_PMP   + 8 * 16 * 1024;
static constexpr int F_MEAN  = F_LMP   + 4 * 16 * 1024;
static constexpr int F_CBSQ  = F_MEAN  + 16 * 2048;
static constexpr int F_STATE = F_CBSQ  + 8192;
static constexpr int F_S2P   = F_STATE + 16 * 1024;
static constexpr int F_QS1   = F_S2P   + 8 * 16 * 1024;
static constexpr int F_QS2   = F_QS1   + 8 * 16 * 1024;
static constexpr int F_ACCST = F_QS2   + 8 * 16 * 1024;
static constexpr int F_LST   = F_ACCST + 64 * 16 * 1024;
static constexpr int F_STCTX = F_LST   + 1024;
static constexpr int F_OPP   = F_STCTX + 8 * 16 * 1024;
static constexpr int F_OPMAX = F_OPP   + 8 * 16 * 1024;       // 256*16 u64
static constexpr int F_QB1   = F_OPMAX + 8192;
static constexpr int F_QB2   = F_QB1   + 8 * 25 * 1025;
static constexpr int F_ACCSL = F_QB2   + 8 * 25 * 1024;
static constexpr int F_LSL   = F_ACCSL + 64 * 16 * 9 * 1024;
static constexpr int F_SSUM  = F_LSL   + 64 * 16 * 9;
static constexpr int F_K8P   = F_SSUM  + 16 * 1024;
static constexpr int F_MS    = F_K8P   + 8 * 16 * 1024;
static constexpr int F_GP    = F_MS    + 16 * 1024;
static constexpr int F_END   = F_GP    + 4 * 16 * 6144;

static SG baseSG() {
  SG p;
  p.Bm = nullptr; p.Bg = nullptr; p.a0 = nullptr; p.a1 = nullptr; p.a2 = nullptr;
  p.out = nullptr; p.w0 = nullptr; p.w1 = nullptr;
  p.M = 16; p.K = 1024; p.N = 1024; p.Ncore = 1024;
  p.KSg = 8; p.NB = 16; p.kslice = 128; p.ksh = 7;
  p.lda = 1024; p.ldb = 1024; p.ldo = 1024;
  p.MA = 16; p.P = 8; p.amode = A_RAW; p.bt = 0; p.mr = 4;
  p.scale = 1.f;
  return p;
}

extern "C" void kernel_launch(void* const* d_in, const int* in_sizes, int n_in,
                              void* d_out, int out_size, void* d_ws, size_t ws_size,
                              hipStream_t stream) {
  (void)in_sizes; (void)n_in; (void)out_size;
  const float* logic  = (const float*)d_in[0];
  const float* prompt = (const float*)d_in[1];
  const float* cbv    = (const float*)d_in[2];
  const float* W_init = (const float*)d_in[3];
  const float* W_pq   = (const float*)d_in[4];
  const float* W_pk   = (const float*)d_in[5];
  const float* W_pv   = (const float*)d_in[6];
  const float* slotq  = (const float*)d_in[7];
  const float* W_sq   = (const float*)d_in[8];
  const float* W_op   = (const float*)d_in[9];
  const float* W_gate = (const float*)d_in[10];
  const float* b_gate = (const float*)d_in[11];
  const float* W_stop = (const float*)d_in[12];
  const float* b_stop = (const float*)d_in[13];
  const float* Wih    = (const float*)d_in[14];
  const float* Whh    = (const float*)d_in[15];
  const float* bih    = (const float*)d_in[16];
  const float* bhh    = (const float*)d_in[17];
  float* out = (float*)d_out;
  float* w = (float*)d_ws;
  (void)ws_size;  // requires F_END*4 = ~47.2 MB of workspace

  const float inv32 = 1.0f / 32.0f;

  // ---- setup ----
  k_meanpsum<<<512, 256, 0, stream>>>(prompt, w + F_PMP, 2048, 256);
  k_meanpsum<<<256, 256, 0, stream>>>(logic, w + F_LMP, 512, 128);
  k_cbsq<<<2048, 256, 0, stream>>>(cbv, w + F_CBSQ);
  k_meancat<<<128, 256, 0, stream>>>(w + F_PMP, w + F_LMP, w + F_MEAN);
  {
    SG p = baseSG();
    p.a0 = w + F_MEAN; p.Bm = W_init; p.out = w + F_S2P;
    p.K = 2048; p.kslice = 256; p.ksh = 8; p.lda = 2048;
    k_sgemm<<<128, 256, 0, stream>>>(p);
  }
  k_s2b<<<64, 256, 0, stream>>>(w + F_S2P, w + F_STATE);

  for (int it = 0; it < 4; ++it) {
    // K1a: qs1 = state @ W_pq (psums)
    {
      SG p = baseSG();
      p.a0 = w + F_STATE; p.Bm = W_pq; p.out = w + F_QS1;
      k_sgemm<<<128, 256, 0, stream>>>(p);
    }
    // K1b: qs2 = (sum qs1) @ W_pk^T / 32
    {
      SG p = baseSG();
      p.amode = A_PSUM; p.a0 = w + F_QS1; p.Bm = W_pk; p.bt = 1;
      p.out = w + F_QS2; p.scale = inv32;
      k_sgemm<<<128, 256, 0, stream>>>(p);
    }
    // K2: flash state attention -> accst/lst
    k_flash_state<<<dim3(16, 16), 256, 0, stream>>>(prompt, w + F_QS2, w + F_ACCST, w + F_LST);
    // K4: stctx = (combine accst/lst) @ W_pv
    {
      SG p = baseSG();
      p.amode = A_FLASH; p.a0 = w + F_ACCST; p.a2 = w + F_LST;
      p.Bm = W_pv; p.out = w + F_STCTX;
      k_sgemm<<<128, 256, 0, stream>>>(p);
    }
    // F1: [K5a: opp = state_ctx @ W_op] + [K6a: qb1 = [state_ctx;slotq] @ [W_sq|W_gate]]
    {
      SG p1 = baseSG();
      p1.amode = A_PSUM; p1.a0 = w + F_STCTX; p1.Bm = W_op; p1.out = w + F_OPP;
      SG p2 = baseSG();
      p2.amode = A_PSRAW; p2.a0 = w + F_STCTX; p2.a1 = slotq;
      p2.Bm = W_sq; p2.Bg = W_gate; p2.M = 25; p2.N = 1025; p2.Ncore = 1024;
      p2.NB = 17; p2.out = w + F_QB1; p2.ldo = 1025; p2.mr = 7;
      k_sgemm2<<<264, 256, 0, stream>>>(p1, p2, 128);
    }
    // F2: [K6b: qb2 = (sum qb1) @ W_pk^T / 32] + [codebook argmax]
    {
      SG p = baseSG();
      p.amode = A_PSUM; p.a0 = w + F_QB1; p.MA = 25; p.lda = 1025;
      p.M = 25; p.Bm = W_pk; p.bt = 1; p.out = w + F_QB2; p.scale = inv32; p.mr = 7;
      k_gemm_cb<<<384, 256, 0, stream>>>(p, w + F_OPP, cbv, w + F_CBSQ,
                                         (unsigned long long*)(w + F_OPMAX));
    }
    // K6f: flash slot attention -> accsl/lsl
    k_flash_slot<<<dim3(16, 16), 256, 0, stream>>>(prompt, w + F_QB2, w + F_ACCSL, w + F_LSL);
    // K7: combine + gates/mask + masked mean -> ssum
    k_k7<<<64, 256, 0, stream>>>(w + F_ACCSL, w + F_LSL, w + F_QB1, b_gate, w + F_SSUM);
    // K8a: k8p = ssum @ W_pv (psums)
    {
      SG p = baseSG();
      p.a0 = w + F_SSUM; p.Bm = W_pv; p.out = w + F_K8P;
      k_sgemm<<<128, 256, 0, stream>>>(p);
    }
    // K9a: [ms=tanh(op_emb+k8p) @ Wih] + [state @ Whh] -> gp psums; side-writes ms + d_out summary
    {
      SG p1 = baseSG();
      p1.amode = A_TANHMS; p1.a0 = w + F_K8P; p1.a1 = cbv; p1.a2 = w + F_OPMAX;
      p1.Bm = Wih; p1.ldb = 3072; p1.N = 3072; p1.Ncore = 3072;
      p1.KSg = 4; p1.kslice = 256; p1.ksh = 8; p1.NB = 48;
      p1.out = w + F_GP; p1.ldo = 6144;
      p1.w0 = w + F_MS; p1.w1 = out + it * 1024;
      SG p2 = baseSG();
      p2.a0 = w + F_STATE; p2.Bm = Whh; p2.ldb = 3072; p2.N = 3072; p2.Ncore = 3072;
      p2.KSg = 4; p2.kslice = 256; p2.ksh = 8; p2.NB = 48;
      p2.out = w + F_GP + 3072; p2.ldo = 6144;
      k_sgemm2<<<384, 256, 0, stream>>>(p1, p2, 192);
    }
    // K9b: GRU finish + stop logits/probs
    k_k9b<<<68, 256, 0, stream>>>(w + F_GP, bih, bhh, w + F_STATE, w + F_STCTX,
                                  w + F_MS, W_stop, b_stop, out, it);
  }
  k_k10<<<1, 64, 0, stream>>>(out);
}

// Round 2
// 1506.458 us; speedup vs baseline: 1.9792x; 1.9792x over previous
//
#include <hip/hip_runtime.h>

// ---------------------------------------------------------------------------
// AutoregressiveMatrixChain on MI355X, fp32.
// R2: occupancy fixes. Slot attention = two-phase (scores -> PV-GEMM with
// split-K psums); state attention = flash with 256 chunks (1024 blocks);
// small GEMMs KSg=16; tiny combine kernels in front of wide consumers.
// ---------------------------------------------------------------------------

#define DINL __device__ __forceinline__

enum { A_RAW = 0, A_PSUM = 1, A_PSRAW = 2 };

struct SG {
  const float* Bm;   // weight [K][N] (or [N][K] if bt)
  const float* Bg;   // extra single column (gate) for n >= Ncore
  const float* a0;   // A source 0
  const float* a1;   // A source 1 (slotq)
  float* out;        // psums [KSg][M][ldo]
  int M, N, Ncore, NB, kslice, ksh, lda, ldb, ldo, MA, P, amode, bt, mr;
  float scale;
};

DINL float dot4(float4 a, float4 b) {
  return fmaf(a.x, b.x, fmaf(a.y, b.y, fmaf(a.z, b.z, a.w * b.w)));
}
DINL unsigned sortable(float f) {
  unsigned u = __float_as_uint(f);
  return (u & 0x80000000u) ? ~u : (u | 0x80000000u);
}
#define AXPY4(A, W, P) \
  { A.x = fmaf(W, P.x, A.x); A.y = fmaf(W, P.y, A.y); A.z = fmaf(W, P.z, A.z); A.w = fmaf(W, P.w, A.w); }

// ---------------------------------------------------------------------------
// small GEMM body: out[ks][m][n] = A[m, kslice]*B[kslice, n] (*scale)
// ---------------------------------------------------------------------------
template <int MR>
DINL void sgemm_body(const SG p, int bx, char* smem) {
  float* As = (float*)smem;                      // up to 4352 floats
  float* Bs = (float*)(smem + 17408);            // 4160 floats
  const int t = threadIdx.x;
  const int ks = bx / p.NB, nb = bx % p.NB;
  const int kslice = p.kslice;
  const int kb = ks * kslice;

  const int tot = p.M * kslice;
  for (int idx = t; idx < tot; idx += 256) {
    const int m = idx >> p.ksh;
    const int kl = idx & (kslice - 1);
    float v = 0.f;
    if (p.amode == A_RAW) {
      v = p.a0[m * p.lda + kb + kl];
    } else if (p.amode == A_PSUM) {
      for (int s = 0; s < p.P; s++) v += p.a0[(s * p.MA + m) * p.lda + kb + kl];
    } else {  // A_PSRAW
      if (m < 16) {
        for (int s = 0; s < p.P; s++) v += p.a0[(s * p.MA + m) * p.lda + kb + kl];
      } else {
        v = p.a1[(m - 16) * 1024 + kb + kl];
      }
    }
    As[(m << p.ksh) + kl] = v;
  }
  __syncthreads();

  const int nl = t & 63, mg = t >> 6;
  const int n = nb * 64 + nl;
  const bool nok = (n < p.N);
  float acc[MR];
#pragma unroll
  for (int i = 0; i < MR; i++) acc[i] = 0.f;

  if (!p.bt) {
    const bool useg = nok && (n >= p.Ncore);
    const float* Bc = p.Bm + n;
    for (int k4 = 0; k4 < kslice; k4 += 4) {
      float bv[4];
#pragma unroll
      for (int u = 0; u < 4; u++) {
        bv[u] = 0.f;
        if (nok) bv[u] = useg ? p.Bg[kb + k4 + u] : Bc[(kb + k4 + u) * p.ldb];
      }
#pragma unroll
      for (int i = 0; i < MR; i++) {
        const int m = mg + 4 * i;
        if (MR == 4 || m < p.M) {
          const float4 av = *(const float4*)&As[(m << p.ksh) + k4];
          acc[i] = fmaf(av.x, bv[0], acc[i]);
          acc[i] = fmaf(av.y, bv[1], acc[i]);
          acc[i] = fmaf(av.z, bv[2], acc[i]);
          acc[i] = fmaf(av.w, bv[3], acc[i]);
        }
      }
    }
  } else {
    // B is [N][K]; stage 64x64 tiles transposed into LDS
    for (int kt = 0; kt < kslice; kt += 64) {
      __syncthreads();
      for (int idx = t; idx < 4096; idx += 256) {
        const int i2 = idx >> 6, j2 = idx & 63;
        Bs[j2 * 65 + i2] = p.Bm[(nb * 64 + i2) * p.ldb + kb + kt + j2];
      }
      __syncthreads();
      for (int k4 = 0; k4 < 64; k4 += 4) {
        float bv[4];
#pragma unroll
        for (int u = 0; u < 4; u++) bv[u] = Bs[(k4 + u) * 65 + nl];
#pragma unroll
        for (int i = 0; i < MR; i++) {
          const int m = mg + 4 * i;
          if (MR == 4 || m < p.M) {
            const float4 av = *(const float4*)&As[(m << p.ksh) + kt + k4];
            acc[i] = fmaf(av.x, bv[0], acc[i]);
            acc[i] = fmaf(av.y, bv[1], acc[i]);
            acc[i] = fmaf(av.z, bv[2], acc[i]);
            acc[i] = fmaf(av.w, bv[3], acc[i]);
          }
        }
      }
    }
  }

  if (nok) {
#pragma unroll
    for (int i = 0; i < MR; i++) {
      const int m = mg + 4 * i;
      if (MR == 4 || m < p.M) p.out[(ks * p.M + m) * p.ldo + n] = acc[i] * p.scale;
    }
  }
}

__global__ __launch_bounds__(256) void k_sgemm(SG p) {
  __shared__ __align__(16) char smem[34176];
  if (p.mr == 4) sgemm_body<4>(p, blockIdx.x, smem);
  else sgemm_body<7>(p, blockIdx.x, smem);
}

__global__ __launch_bounds__(256) void k_sgemm2(SG p1, SG p2, int split) {
  __shared__ __align__(16) char smem[34176];
  const int bx = blockIdx.x;
  const SG& p = (bx < split) ? p1 : p2;
  const int b2 = (bx < split) ? bx : bx - split;
  if (p.mr == 4) sgemm_body<4>(p, b2, smem);
  else sgemm_body<7>(p, b2, smem);
}

// ---------------------------------------------------------------------------
// fused: [K6b sgemm (blocks 0..255)] + [codebook argmax (blocks 256..511)]
// cb part reads pre-combined opv[16][1024]; packed-u64 max -> opmax[256][16].
// ---------------------------------------------------------------------------
__global__ __launch_bounds__(256) void k_gemm_cb(SG p, const float* __restrict__ opv,
                                                 const float* __restrict__ cbv,
                                                 const float* __restrict__ cbsqv,
                                                 unsigned long long* __restrict__ opmaxp) {
  __shared__ __align__(16) char smem[65536];
  const int bx = blockIdx.x;
  if (bx < 256) {
    sgemm_body<7>(p, bx, smem);
    return;
  }
  const int bx2 = bx - 256;
  const int t = threadIdx.x;
  for (int idx = t; idx < 16384; idx += 256) {
    const int x = idx << 2;
    *(float*)(smem + (x ^ (((x >> 7) & 7) << 4))) = opv[idx];
  }
  __syncthreads();
  const int w = t >> 6, l = t & 63;
  const int bxl = 64 * l;
  const int key = ((bxl >> 7) & 7) << 4;
  const int o0 = bxl ^ key, o1 = (bxl + 16) ^ key, o2 = (bxl + 32) ^ key, o3 = (bxl + 48) ^ key;
  unsigned long long bk[16];
#pragma unroll
  for (int m = 0; m < 16; m++) bk[m] = 0ull;
  const int cbase = (bx2 << 5) + (w << 3);
  for (int ci = 0; ci < 8; ci++) {
    const int c = cbase + ci;
    const float4* cr = (const float4*)(cbv + (c << 10));
    const float4 c0 = cr[4 * l], c1 = cr[4 * l + 1], c2 = cr[4 * l + 2], c3 = cr[4 * l + 3];
    float sm[16];
#pragma unroll
    for (int m = 0; m < 16; m++) {
      const char* qp = smem + (m << 12);
      const float4 a0 = *(const float4*)(qp + o0);
      const float4 a1 = *(const float4*)(qp + o1);
      const float4 a2 = *(const float4*)(qp + o2);
      const float4 a3 = *(const float4*)(qp + o3);
      sm[m] = dot4(a0, c0) + dot4(a1, c1) + dot4(a2, c2) + dot4(a3, c3);
    }
#pragma unroll
    for (int off = 32; off > 0; off >>= 1) {
#pragma unroll
      for (int m = 0; m < 16; m++) sm[m] += __shfl_xor(sm[m], off);
    }
    const float cq = cbsqv[c];
#pragma unroll
    for (int m = 0; m < 16; m++) {
      const float sc = fmaf(2.f, sm[m], -cq);
      const unsigned long long k2 = ((unsigned long long)sortable(sc) << 32) | (unsigned)(8192 - c);
      bk[m] = k2 > bk[m] ? k2 : bk[m];
    }
  }
  __syncthreads();
  unsigned long long* red = (unsigned long long*)smem;
  if (l == 0) {
#pragma unroll
    for (int m = 0; m < 16; m++) red[w * 16 + m] = bk[m];
  }
  __syncthreads();
  if (t < 16) {
    unsigned long long b2 = red[t];
    for (int ww = 1; ww < 4; ww++) {
      const unsigned long long v = red[ww * 16 + t];
      b2 = v > b2 ? v : b2;
    }
    opmaxp[bx2 * 16 + t] = b2;
  }
}

// ---------------------------------------------------------------------------
// flash attention, state pass: Q=1/batch, 256 chunks of 8 keys. grid (64,16).
// ---------------------------------------------------------------------------
__global__ __launch_bounds__(256) void k_flash_state(const float* __restrict__ prompt,
                                                     const float* __restrict__ qsv,
                                                     float* __restrict__ accst,
                                                     float* __restrict__ lst) {
  const int b = blockIdx.y;
  const int w = threadIdx.x >> 6, l = threadIdx.x & 63;
  const int chunk = blockIdx.x * 4 + w;  // 0..255
  const float4* qp = (const float4*)(qsv + (b << 10) + 16 * l);
  const float4 q0 = qp[0], q1 = qp[1], q2 = qp[2], q3 = qp[3];
  float4 acc[4];
#pragma unroll
  for (int r = 0; r < 4; r++) acc[r] = make_float4(0.f, 0.f, 0.f, 0.f);
  float lsum = 0.f;
  const float* pbase = prompt + ((b * 2048 + chunk * 8) << 10) + 16 * l;
  for (int k = 0; k < 8; k++) {
    const float4* pr = (const float4*)(pbase + (k << 10));
    const float4 p0 = pr[0], p1 = pr[1], p2 = pr[2], p3 = pr[3];
    float s = dot4(q0, p0) + dot4(q1, p1) + dot4(q2, p2) + dot4(q3, p3);
#pragma unroll
    for (int off = 32; off > 0; off >>= 1) s += __shfl_xor(s, off);
    const float wgt = __expf(s);
    lsum += wgt;
    AXPY4(acc[0], wgt, p0); AXPY4(acc[1], wgt, p1);
    AXPY4(acc[2], wgt, p2); AXPY4(acc[3], wgt, p3);
  }
  float* ob = accst + ((chunk * 16 + b) << 10) + 16 * l;
#pragma unroll
  for (int r = 0; r < 4; r++) ((float4*)ob)[r] = acc[r];
  if (l == 0) lst[chunk * 16 + b] = lsum;
}

// combine state flash psums: ctx[b][h] = sum_c acc / sum_c l
__global__ __launch_bounds__(256) void k_cst(const float* __restrict__ accst,
                                             const float* __restrict__ lst,
                                             float* __restrict__ ctx) {
  __shared__ float rinv;
  const int bx = blockIdx.x;  // 64
  const int b = bx >> 2;
  const int t = threadIdx.x;
  if (t < 64) {
    float s = 0.f;
    for (int c = t; c < 256; c += 64) s += lst[c * 16 + b];
#pragma unroll
    for (int off = 32; off > 0; off >>= 1) s += __shfl_xor(s, off);
    if (t == 0) rinv = 1.f / s;
  }
  __syncthreads();
  const int h = ((bx & 3) << 8) + t;
  float v = 0.f;
  for (int c = 0; c < 256; c++) v += accst[((c * 16 + b) << 10) + h];
  ctx[(b << 10) + h] = v * rinv;
}

// generic psum combine: dst[i] = sum_p src[p*stride + i]
__global__ __launch_bounds__(256) void k_comb(const float* __restrict__ src,
                                              float* __restrict__ dst, int P, int stride) {
  const int i = blockIdx.x * 256 + threadIdx.x;
  float s = 0.f;
  for (int p = 0; p < P; p++) s += src[p * stride + i];
  dst[i] = s;
}

// argmax finish: opidx[b] from opmax[256][16]
__global__ void k_amax(const unsigned long long* __restrict__ opmax, int* __restrict__ opidx) {
  __shared__ unsigned long long red[256];
  const int t = threadIdx.x;
  const int b = t & 15, part = t >> 4;
  unsigned long long best = 0ull;
  for (int c = part * 16; c < part * 16 + 16; c++) {
    const unsigned long long v = opmax[c * 16 + b];
    best = v > best ? v : best;
  }
  red[t] = best;
  __syncthreads();
  if (t < 16) {
    unsigned long long m = red[t];
    for (int p2 = 1; p2 < 16; p2++) {
      const unsigned long long v = red[p2 * 16 + t];
      m = v > m ? v : m;
    }
    opidx[t] = 8192 - (int)(unsigned)(m & 0xFFFFFFFFull);
  }
}

// slot query combine: qsl[b][j][h] = sum_p (qb2[p][b][h] + qb2[p][16+j][h])
__global__ __launch_bounds__(256) void k_qcomb(const float* __restrict__ qb2,
                                               float* __restrict__ qsl) {
  const int i = blockIdx.x * 256 + threadIdx.x;  // < 147456
  const int h = i & 1023;
  const int r = i >> 10;  // 0..143
  const int b = r / 9, j = r - b * 9;
  float s = 0.f;
  for (int p = 0; p < 16; p++) {
    const float* q = qb2 + p * 25600;
    s += q[(b << 10) + h] + q[((16 + j) << 10) + h];
  }
  qsl[i] = s;
}

// ---------------------------------------------------------------------------
// slot scores: wexp[b][k][9] = exp(q_j . p_k); lpsum per 16-key wave chunk.
// grid (32, 16), 256 threads, wave w handles keys bx*64 + w*16 + [0,16).
// ---------------------------------------------------------------------------
__global__ __launch_bounds__(256) void k_scores(const float* __restrict__ prompt,
                                                const float* __restrict__ qsl,
                                                float* __restrict__ wexp,
                                                float* __restrict__ lpsum) {
  __shared__ __align__(16) char qsm[36864];
  const int b = blockIdx.y;
  const int t = threadIdx.x;
  for (int idx = t; idx < 9216; idx += 256) {
    const int x = idx << 2;
    *(float*)(qsm + (x ^ (((x >> 7) & 7) << 4))) = qsl[b * 9216 + idx];
  }
  __syncthreads();
  const int w = t >> 6, l = t & 63;
  const int bxl = 64 * l;
  const int key = ((bxl >> 7) & 7) << 4;
  const int o0 = bxl ^ key, o1 = (bxl + 16) ^ key, o2 = (bxl + 32) ^ key, o3 = (bxl + 48) ^ key;
  const int k0 = blockIdx.x * 64 + w * 16;
  float lacc = 0.f;
  const float* pbase = prompt + ((b * 2048 + k0) << 10) + 16 * l;
  for (int ki = 0; ki < 16; ki++) {
    const float4* pr = (const float4*)(pbase + (ki << 10));
    const float4 p0 = pr[0], p1 = pr[1], p2 = pr[2], p3 = pr[3];
    float sj[9];
#pragma unroll
    for (int j = 0; j < 9; j++) {
      const char* qp = qsm + (j << 12);
      sj[j] = dot4(*(const float4*)(qp + o0), p0) + dot4(*(const float4*)(qp + o1), p1) +
              dot4(*(const float4*)(qp + o2), p2) + dot4(*(const float4*)(qp + o3), p3);
    }
#pragma unroll
    for (int off = 32; off > 0; off >>= 1) {
#pragma unroll
      for (int j = 0; j < 9; j++) sj[j] += __shfl_xor(sj[j], off);
    }
    float wv = sj[0];
#pragma unroll
    for (int j = 1; j < 9; j++)
      if (l == j) wv = sj[j];
    if (l < 9) {
      const float e = __expf(wv);
      wexp[(b * 2048 + k0 + ki) * 9 + l] = e;
      lacc += e;
    }
  }
  if (l < 9) lpsum[(b * 128 + blockIdx.x * 4 + w) * 9 + l] = lacc;
}

// ---------------------------------------------------------------------------
// slot PV: accp[chunk][b][j][h] = sum_{k in chunk} wexp[b][k][j] * p[b][k][h]
// grid (64, 16): kc = bx>>3 (8 x 256 keys), hb = bx&7 (8 x 128 h). 32 chunks.
// ---------------------------------------------------------------------------
__global__ __launch_bounds__(256) void k_pv(const float* __restrict__ prompt,
                                            const float* __restrict__ wexp,
                                            float* __restrict__ accp) {
  __shared__ float wl[2304];
  const int b = blockIdx.y;
  const int kc = blockIdx.x >> 3;
  const int hb = blockIdx.x & 7;
  const int t = threadIdx.x;
  for (int idx = t; idx < 2304; idx += 256) wl[idx] = wexp[(b * 2048 + kc * 256) * 9 + idx];
  __syncthreads();
  const int w = t >> 6, l = t & 63;
  const int chunk = kc * 4 + w;
  const int h = hb * 128 + l * 2;
  float2 acc[9];
#pragma unroll
  for (int j = 0; j < 9; j++) acc[j] = make_float2(0.f, 0.f);
  const float* pb = prompt + ((b * 2048 + kc * 256 + w * 64) << 10) + h;
  for (int k = 0; k < 64; k++) {
    const float2 p2 = *(const float2*)(pb + (k << 10));
    const float* wr = &wl[(w * 64 + k) * 9];
#pragma unroll
    for (int j = 0; j < 9; j++) {
      acc[j].x = fmaf(wr[j], p2.x, acc[j].x);
      acc[j].y = fmaf(wr[j], p2.y, acc[j].y);
    }
  }
  float* ob = accp + (((chunk * 16 + b) * 9) << 10) + h;
#pragma unroll
  for (int j = 0; j < 9; j++) *(float2*)(ob + (j << 10)) = acc[j];
}

// ---------------------------------------------------------------------------
// K7: combine slot PV psums, gates + mask (+global fallback), masked mean
// ---------------------------------------------------------------------------
__global__ __launch_bounds__(256) void k_k7(const float* __restrict__ accp,
                                            const float* __restrict__ lpsum,
                                            const float* __restrict__ qb1,
                                            const float* __restrict__ bgate,
                                            float* __restrict__ ssum) {
  __shared__ float rl[9];
  __shared__ float gpre[25];
  __shared__ int mask_s[9];
  __shared__ float cntInv;
  const int bx = blockIdx.x;
  const int b = bx >> 2;
  const int t = threadIdx.x;
  if (t < 9) {
    float s = 0.f;
    for (int c = 0; c < 128; c++) s += lpsum[(b * 128 + c) * 9 + t];
    rl[t] = 1.f / s;
  }
  if (t >= 32 && t < 57) {
    const int m = t - 32;
    float s = 0.f;
    for (int si = 0; si < 16; si++) s += qb1[(si * 25 + m) * 1025 + 1024];
    gpre[m] = s;
  }
  __syncthreads();
  if (t == 0) {
    const float bg = bgate[0];
    bool any = false;
    for (int bb = 0; bb < 16; bb++)
      for (int j = 0; j < 9; j++)
        if (gpre[bb] + gpre[16 + j] + bg >= 0.f) any = true;
    int cnt = 0;
    if (any) {
      for (int j = 0; j < 9; j++) {
        const int s = (gpre[b] + gpre[16 + j] + bg >= 0.f) ? 1 : 0;
        mask_s[j] = s;
        cnt += s;
      }
    } else {
      float bv = -3.4e38f;
      int bj = 0;
      for (int j = 0; j < 9; j++) {
        const float v = gpre[b] + gpre[16 + j] + bg;
        if (v > bv) { bv = v; bj = j; }
      }
      for (int j = 0; j < 9; j++) mask_s[j] = (j == bj) ? 1 : 0;
      cnt = 1;
    }
    cntInv = 1.f / (float)(cnt > 0 ? cnt : 1);
  }
  __syncthreads();
  const int h = ((bx & 3) << 8) + t;
  float v = 0.f;
  for (int j = 0; j < 9; j++) {
    if (mask_s[j]) {
      float s = 0.f;
      for (int c = 0; c < 32; c++) s += accp[(((c * 16 + b) * 9 + j) << 10) + h];
      v = fmaf(s, rl[j], v);
    }
  }
  ssum[(b << 10) + h] = v * cntInv;
}

// ms = tanh(sum_p k8p + codebook[opidx]); side-writes d_out summary
__global__ __launch_bounds__(256) void k_msc(const float* __restrict__ k8p,
                                             const int* __restrict__ opidx,
                                             const float* __restrict__ cbv,
                                             float* __restrict__ ms,
                                             float* __restrict__ dout, int it) {
  const int i = blockIdx.x * 256 + threadIdx.x;  // < 16384
  const int b = i >> 10, h = i & 1023;
  float s = 0.f;
  for (int p = 0; p < 16; p++) s += k8p[p * 16384 + i];
  const float v = tanhf(s + cbv[(opidx[b] << 10) + h]);
  ms[i] = v;
  dout[(b << 12) + (it << 10) + h] = v;
}

// ---------------------------------------------------------------------------
// K9b: GRU elementwise finish (blocks 0..63) + stop logits (blocks 64..67)
// ---------------------------------------------------------------------------
__global__ __launch_bounds__(256) void k_k9b(const float* __restrict__ gp,
                                             const float* __restrict__ bih,
                                             const float* __restrict__ bhh,
                                             float* __restrict__ state,
                                             const float* __restrict__ stctx,
                                             const float* __restrict__ ms,
                                             const float* __restrict__ Wstop,
                                             const float* __restrict__ bstop,
                                             float* __restrict__ dout, int it) {
  const int bx = blockIdx.x;
  const int t = threadIdx.x;
  if (bx < 64) {
    const int gi = bx * 256 + t;
    const int b = gi >> 10, h = gi & 1023;
    float ir = 0.f, iz = 0.f, inn = 0.f, hr = 0.f, hz = 0.f, hn = 0.f;
    for (int s = 0; s < 8; s++) {
      const float* g = gp + (s * 16 + b) * 6144;
      ir += g[h]; iz += g[1024 + h]; inn += g[2048 + h];
      hr += g[3072 + h]; hz += g[4096 + h]; hn += g[5120 + h];
    }
    ir += bih[h]; iz += bih[1024 + h]; inn += bih[2048 + h];
    hr += bhh[h]; hz += bhh[1024 + h]; hn += bhh[2048 + h];
    const float r = 1.f / (1.f + __expf(-(ir + hr)));
    const float z = 1.f / (1.f + __expf(-(iz + hz)));
    const float n = tanhf(fmaf(r, hn, inn));
    const float hold = state[gi];
    state[gi] = (1.f - z) * n + z * hold;
  } else {
    const int wid = (bx - 64) * 4 + (t >> 6);
    const int l = t & 63;
    float p = 0.f;
    for (int i = 0; i < 16; i++) {
      const int h = l + (i << 6);
      float sc = 0.f;
      for (int s = 0; s < 16; s++) sc += stctx[((s * 16 + wid) << 10) + h];
      p = fmaf(sc, Wstop[h], p);
      p = fmaf(ms[(wid << 10) + h], Wstop[1024 + h], p);
    }
#pragma unroll
    for (int off = 32; off > 0; off >>= 1) p += __shfl_xor(p, off);
    if (l == 0) {
      const float lg = p + bstop[0];
      dout[65536 + wid * 4 + it] = lg;
      dout[65600 + wid * 4 + it] = 1.f / (1.f + __expf(-lg));
    }
  }
}

__global__ void k_k10(float* __restrict__ dout) {
  const int t = threadIdx.x;
  if (t < 16) {
    int cl = 4;
    for (int it = 0; it < 4; it++) {
      if (dout[65536 + t * 4 + it] >= 0.f) { cl = it + 1; break; }
    }
    dout[65664 + t] = (float)cl;
  }
}

// --------------------------- setup kernels ---------------------------------
__global__ __launch_bounds__(256) void k_meanpsum(const float* __restrict__ src,
                                                  float* __restrict__ out, int Rtot, int rps) {
  const int bx = blockIdx.x;
  const int s = bx >> 6, b = (bx >> 2) & 15, hb = bx & 3;
  const int h = hb * 256 + threadIdx.x;
  float v = 0.f;
  const int r0 = s * rps;
  for (int r = 0; r < rps; r++) v += src[(b * Rtot + r0 + r) * 1024 + h];
  out[((s * 16 + b) << 10) + h] = v;
}

__global__ __launch_bounds__(256) void k_cbsq(const float* __restrict__ cbv,
                                              float* __restrict__ out) {
  const int c = blockIdx.x * 4 + (threadIdx.x >> 6);
  const int l = threadIdx.x & 63;
  const float4* cr = (const float4*)(cbv + (c << 10));
  float s = 0.f;
#pragma unroll
  for (int r = 0; r < 4; r++) {
    const float4 v = cr[4 * l + r];
    s += dot4(v, v);
  }
#pragma unroll
  for (int off = 32; off > 0; off >>= 1) s += __shfl_xor(s, off);
  if (l == 0) out[c] = s;
}

__global__ __launch_bounds__(256) void k_meancat(const float* __restrict__ pmp,
                                                 const float* __restrict__ lmp,
                                                 float* __restrict__ mean) {
  const int gi = blockIdx.x * 256 + threadIdx.x;
  const int b = gi >> 11, k = gi & 2047;
  float v = 0.f;
  if (k < 1024) {
    for (int s = 0; s < 8; s++) v += pmp[((s * 16 + b) << 10) + k];
    v *= (1.f / 2048.f);
  } else {
    const int kk = k - 1024;
    for (int s = 0; s < 4; s++) v += lmp[((s * 16 + b) << 10) + kk];
    v *= (1.f / 512.f);
  }
  mean[b * 2048 + k] = v;
}

__global__ __launch_bounds__(256) void k_s2b(const float* __restrict__ s2p,
                                             float* __restrict__ state) {
  const int gi = blockIdx.x * 256 + threadIdx.x;
  const int b = gi >> 10, h = gi & 1023;
  float s = 0.f;
  for (int si = 0; si < 8; si++) s += s2p[((si * 16 + b) << 10) + h];
  state[gi] = tanhf(s);
}

// ---------------------------------------------------------------------------
// workspace layout (floats); total ~8.58M floats (~34.3 MB)
// ---------------------------------------------------------------------------
static constexpr int F_PMP   = 0;
static constexpr int F_LMP   = F_PMP   + 131072;
static constexpr int F_MEAN  = F_LMP   + 65536;
static constexpr int F_CBSQ  = F_MEAN  + 32768;
static constexpr int F_STATE = F_CBSQ  + 8192;
static constexpr int F_S2P   = F_STATE + 16384;
static constexpr int F_QS1   = F_S2P   + 131072;
static constexpr int F_QS2   = F_QS1   + 262144;
static constexpr int F_QSV   = F_QS2   + 262144;
static constexpr int F_LST   = F_QSV   + 16384;
static constexpr int F_CTX   = F_LST   + 4096;
static constexpr int F_STCTX = F_CTX   + 16384;
static constexpr int F_OPP   = F_STCTX + 262144;
static constexpr int F_OPV   = F_OPP   + 262144;
static constexpr int F_OPMAX = F_OPV   + 16384;   // u64[4096]
static constexpr int F_OPIDX = F_OPMAX + 8192;    // int[16]
static constexpr int F_QB1   = F_OPIDX + 64;
static constexpr int F_QB2   = F_QB1   + 410000;
static constexpr int F_QSL   = F_QB2   + 409600;
static constexpr int F_WEXP  = F_QSL   + 147456;
static constexpr int F_LPS   = F_WEXP  + 294912;
static constexpr int F_SSUM  = F_LPS   + 18432;
static constexpr int F_K8P   = F_SSUM  + 16384;
static constexpr int F_MS    = F_K8P   + 262144;
static constexpr int F_GP    = F_MS    + 16384;
static constexpr int F_BIG   = F_GP    + 786432;  // accst (4.2M) / accp (4.7M) overlap
static constexpr int F_END   = F_BIG   + 4718592;

static SG baseSG() {
  SG p;
  p.Bm = nullptr; p.Bg = nullptr; p.a0 = nullptr; p.a1 = nullptr; p.out = nullptr;
  p.M = 16; p.N = 1024; p.Ncore = 1024;
  p.NB = 16; p.kslice = 64; p.ksh = 6;
  p.lda = 1024; p.ldb = 1024; p.ldo = 1024;
  p.MA = 16; p.P = 16; p.amode = A_RAW; p.bt = 0; p.mr = 4;
  p.scale = 1.f;
  return p;
}

extern "C" void kernel_launch(void* const* d_in, const int* in_sizes, int n_in,
                              void* d_out, int out_size, void* d_ws, size_t ws_size,
                              hipStream_t stream) {
  (void)in_sizes; (void)n_in; (void)out_size; (void)ws_size;
  const float* logic  = (const float*)d_in[0];
  const float* prompt = (const float*)d_in[1];
  const float* cbv    = (const float*)d_in[2];
  const float* W_init = (const float*)d_in[3];
  const float* W_pq   = (const float*)d_in[4];
  const float* W_pk   = (const float*)d_in[5];
  const float* W_pv   = (const float*)d_in[6];
  const float* slotq  = (const float*)d_in[7];
  const float* W_sq   = (const float*)d_in[8];
  const float* W_op   = (const float*)d_in[9];
  const float* W_gate = (const float*)d_in[10];
  const float* b_gate = (const float*)d_in[11];
  const float* W_stop = (const float*)d_in[12];
  const float* b_stop = (const float*)d_in[13];
  const float* Wih    = (const float*)d_in[14];
  const float* Whh    = (const float*)d_in[15];
  const float* bih    = (const float*)d_in[16];
  const float* bhh    = (const float*)d_in[17];
  float* out = (float*)d_out;
  float* w = (float*)d_ws;

  const float inv32 = 1.0f / 32.0f;

  // ---- setup ----
  k_meanpsum<<<512, 256, 0, stream>>>(prompt, w + F_PMP, 2048, 256);
  k_meanpsum<<<256, 256, 0, stream>>>(logic, w + F_LMP, 512, 128);
  k_cbsq<<<2048, 256, 0, stream>>>(cbv, w + F_CBSQ);
  k_meancat<<<128, 256, 0, stream>>>(w + F_PMP, w + F_LMP, w + F_MEAN);
  {
    SG p = baseSG();
    p.a0 = w + F_MEAN; p.Bm = W_init; p.out = w + F_S2P;
    p.kslice = 256; p.ksh = 8; p.lda = 2048; p.NB = 16;  // KSg=8 -> 128 blocks
    k_sgemm<<<128, 256, 0, stream>>>(p);
  }
  k_s2b<<<64, 256, 0, stream>>>(w + F_S2P, w + F_STATE);

  for (int it = 0; it < 4; ++it) {
    // K1a: qs1 = state @ W_pq (16 psums)
    {
      SG p = baseSG();
      p.a0 = w + F_STATE; p.Bm = W_pq; p.out = w + F_QS1;
      k_sgemm<<<256, 256, 0, stream>>>(p);
    }
    // K1b: qs2 = (sum qs1) @ W_pk^T / 32
    {
      SG p = baseSG();
      p.amode = A_PSUM; p.a0 = w + F_QS1; p.Bm = W_pk; p.bt = 1;
      p.out = w + F_QS2; p.scale = inv32;
      k_sgemm<<<256, 256, 0, stream>>>(p);
    }
    // qs2 psums -> qsv
    k_comb<<<64, 256, 0, stream>>>(w + F_QS2, w + F_QSV, 16, 16384);
    // K2: flash state attention (256 chunks)
    k_flash_state<<<dim3(64, 16), 256, 0, stream>>>(prompt, w + F_QSV, w + F_BIG, w + F_LST);
    // combine + normalize -> ctx
    k_cst<<<64, 256, 0, stream>>>(w + F_BIG, w + F_LST, w + F_CTX);
    // K4: stctx = ctx @ W_pv (16 psums)
    {
      SG p = baseSG();
      p.a0 = w + F_CTX; p.Bm = W_pv; p.out = w + F_STCTX;
      k_sgemm<<<256, 256, 0, stream>>>(p);
    }
    // F1: [opp = state_ctx @ W_op] + [qb1 = [state_ctx;slotq] @ [W_sq|W_gate]]
    {
      SG p1 = baseSG();
      p1.amode = A_PSUM; p1.a0 = w + F_STCTX; p1.Bm = W_op; p1.out = w + F_OPP;
      SG p2 = baseSG();
      p2.amode = A_PSRAW; p2.a0 = w + F_STCTX; p2.a1 = slotq;
      p2.Bm = W_sq; p2.Bg = W_gate; p2.M = 25; p2.N = 1025; p2.Ncore = 1024;
      p2.NB = 17; p2.out = w + F_QB1; p2.ldo = 1025; p2.mr = 7;
      k_sgemm2<<<528, 256, 0, stream>>>(p1, p2, 256);
    }
    // opp psums -> opv
    k_comb<<<64, 256, 0, stream>>>(w + F_OPP, w + F_OPV, 16, 16384);
    // F2: [qb2 = (sum qb1) @ W_pk^T / 32] + [codebook argmax]
    {
      SG p = baseSG();
      p.amode = A_PSUM; p.a0 = w + F_QB1; p.MA = 25; p.lda = 1025;
      p.M = 25; p.Bm = W_pk; p.bt = 1; p.out = w + F_QB2; p.scale = inv32; p.mr = 7;
      k_gemm_cb<<<512, 256, 0, stream>>>(p, w + F_OPV, cbv, w + F_CBSQ,
                                         (unsigned long long*)(w + F_OPMAX));
    }
    k_amax<<<1, 256, 0, stream>>>((const unsigned long long*)(w + F_OPMAX),
                                  (int*)(w + F_OPIDX));
    // qb2 psums -> combined slot queries qsl[b][j][h]
    k_qcomb<<<576, 256, 0, stream>>>(w + F_QB2, w + F_QSL);
    // slot scores + PV
    k_scores<<<dim3(32, 16), 256, 0, stream>>>(prompt, w + F_QSL, w + F_WEXP, w + F_LPS);
    k_pv<<<dim3(64, 16), 256, 0, stream>>>(prompt, w + F_WEXP, w + F_BIG);
    // K7: combine + gates/mask + masked mean -> ssum
    k_k7<<<64, 256, 0, stream>>>(w + F_BIG, w + F_LPS, w + F_QB1, b_gate, w + F_SSUM);
    // K8a: k8p = ssum @ W_pv (16 psums)
    {
      SG p = baseSG();
      p.a0 = w + F_SSUM; p.Bm = W_pv; p.out = w + F_K8P;
      k_sgemm<<<256, 256, 0, stream>>>(p);
    }
    // ms = tanh(op_emb + slot_summary); writes d_out summary
    k_msc<<<64, 256, 0, stream>>>(w + F_K8P, (const int*)(w + F_OPIDX), cbv,
                                  w + F_MS, out, it);
    // K9a: [ms @ Wih] + [state @ Whh] -> gp (8 psums each)
    {
      SG p1 = baseSG();
      p1.a0 = w + F_MS; p1.Bm = Wih; p1.ldb = 3072; p1.N = 3072; p1.Ncore = 3072;
      p1.kslice = 128; p1.ksh = 7; p1.NB = 48;
      p1.out = w + F_GP; p1.ldo = 6144;
      SG p2 = baseSG();
      p2.a0 = w + F_STATE; p2.Bm = Whh; p2.ldb = 3072; p2.N = 3072; p2.Ncore = 3072;
      p2.kslice = 128; p2.ksh = 7; p2.NB = 48;
      p2.out = w + F_GP + 3072; p2.ldo = 6144;
      k_sgemm2<<<768, 256, 0, stream>>>(p1, p2, 384);
    }
    // K9b: GRU finish + stop logits/probs
    k_k9b<<<68, 256, 0, stream>>>(w + F_GP, bih, bhh, w + F_STATE, w + F_STCTX,
                                  w + F_MS, W_stop, b_stop, out, it);
  }
  k_k10<<<1, 64, 0, stream>>>(out);
}

// Round 3
// 1330.289 us; speedup vs baseline: 2.2413x; 1.1324x over previous
//
#include <hip/hip_runtime.h>

// ---------------------------------------------------------------------------
// AutoregressiveMatrixChain on MI355X, fp32.
// R3: latency fixes. float4 means; parallel psum combines (k_cst 256 blocks);
// flash chunks 128, PV chunks 16; amax fused into qcomb; unrolled PV.
// ---------------------------------------------------------------------------

#define DINL __device__ __forceinline__

enum { A_RAW = 0, A_PSUM = 1, A_PSRAW = 2 };

struct SG {
  const float* Bm;   // weight [K][N] (or [N][K] if bt)
  const float* Bg;   // extra single column (gate) for n >= Ncore
  const float* a0;   // A source 0
  const float* a1;   // A source 1 (slotq)
  float* out;        // psums [KSg][M][ldo]
  int M, N, Ncore, NB, kslice, ksh, lda, ldb, ldo, MA, P, amode, bt, mr;
  float scale;
};

DINL float dot4(float4 a, float4 b) {
  return fmaf(a.x, b.x, fmaf(a.y, b.y, fmaf(a.z, b.z, a.w * b.w)));
}
DINL unsigned sortable(float f) {
  unsigned u = __float_as_uint(f);
  return (u & 0x80000000u) ? ~u : (u | 0x80000000u);
}
#define AXPY4(A, W, P) \
  { A.x = fmaf(W, P.x, A.x); A.y = fmaf(W, P.y, A.y); A.z = fmaf(W, P.z, A.z); A.w = fmaf(W, P.w, A.w); }
#define ADD4(A, V) { A.x += V.x; A.y += V.y; A.z += V.z; A.w += V.w; }

// ---------------------------------------------------------------------------
// small GEMM body: out[ks][m][n] = A[m, kslice]*B[kslice, n] (*scale)
// ---------------------------------------------------------------------------
template <int MR>
DINL void sgemm_body(const SG p, int bx, char* smem) {
  float* As = (float*)smem;                      // up to 4352 floats
  float* Bs = (float*)(smem + 17408);            // 4160 floats
  const int t = threadIdx.x;
  const int ks = bx / p.NB, nb = bx % p.NB;
  const int kslice = p.kslice;
  const int kb = ks * kslice;

  const int tot = p.M * kslice;
  for (int idx = t; idx < tot; idx += 256) {
    const int m = idx >> p.ksh;
    const int kl = idx & (kslice - 1);
    float v = 0.f;
    if (p.amode == A_RAW) {
      v = p.a0[m * p.lda + kb + kl];
    } else if (p.amode == A_PSUM) {
      for (int s = 0; s < p.P; s++) v += p.a0[(s * p.MA + m) * p.lda + kb + kl];
    } else {  // A_PSRAW
      if (m < 16) {
        for (int s = 0; s < p.P; s++) v += p.a0[(s * p.MA + m) * p.lda + kb + kl];
      } else {
        v = p.a1[(m - 16) * 1024 + kb + kl];
      }
    }
    As[(m << p.ksh) + kl] = v;
  }
  __syncthreads();

  const int nl = t & 63, mg = t >> 6;
  const int n = nb * 64 + nl;
  const bool nok = (n < p.N);
  float acc[MR];
#pragma unroll
  for (int i = 0; i < MR; i++) acc[i] = 0.f;

  if (!p.bt) {
    const bool useg = nok && (n >= p.Ncore);
    const float* Bc = p.Bm + n;
    for (int k4 = 0; k4 < kslice; k4 += 4) {
      float bv[4];
#pragma unroll
      for (int u = 0; u < 4; u++) {
        bv[u] = 0.f;
        if (nok) bv[u] = useg ? p.Bg[kb + k4 + u] : Bc[(kb + k4 + u) * p.ldb];
      }
#pragma unroll
      for (int i = 0; i < MR; i++) {
        const int m = mg + 4 * i;
        if (MR == 4 || m < p.M) {
          const float4 av = *(const float4*)&As[(m << p.ksh) + k4];
          acc[i] = fmaf(av.x, bv[0], acc[i]);
          acc[i] = fmaf(av.y, bv[1], acc[i]);
          acc[i] = fmaf(av.z, bv[2], acc[i]);
          acc[i] = fmaf(av.w, bv[3], acc[i]);
        }
      }
    }
  } else {
    // B is [N][K]; stage 64x64 tiles transposed into LDS
    for (int kt = 0; kt < kslice; kt += 64) {
      __syncthreads();
      for (int idx = t; idx < 4096; idx += 256) {
        const int i2 = idx >> 6, j2 = idx & 63;
        Bs[j2 * 65 + i2] = p.Bm[(nb * 64 + i2) * p.ldb + kb + kt + j2];
      }
      __syncthreads();
      for (int k4 = 0; k4 < 64; k4 += 4) {
        float bv[4];
#pragma unroll
        for (int u = 0; u < 4; u++) bv[u] = Bs[(k4 + u) * 65 + nl];
#pragma unroll
        for (int i = 0; i < MR; i++) {
          const int m = mg + 4 * i;
          if (MR == 4 || m < p.M) {
            const float4 av = *(const float4*)&As[(m << p.ksh) + kt + k4];
            acc[i] = fmaf(av.x, bv[0], acc[i]);
            acc[i] = fmaf(av.y, bv[1], acc[i]);
            acc[i] = fmaf(av.z, bv[2], acc[i]);
            acc[i] = fmaf(av.w, bv[3], acc[i]);
          }
        }
      }
    }
  }

  if (nok) {
#pragma unroll
    for (int i = 0; i < MR; i++) {
      const int m = mg + 4 * i;
      if (MR == 4 || m < p.M) p.out[(ks * p.M + m) * p.ldo + n] = acc[i] * p.scale;
    }
  }
}

__global__ __launch_bounds__(256) void k_sgemm(SG p) {
  __shared__ __align__(16) char smem[34176];
  if (p.mr == 4) sgemm_body<4>(p, blockIdx.x, smem);
  else sgemm_body<7>(p, blockIdx.x, smem);
}

__global__ __launch_bounds__(256) void k_sgemm2(SG p1, SG p2, int split) {
  __shared__ __align__(16) char smem[34176];
  const int bx = blockIdx.x;
  const SG& p = (bx < split) ? p1 : p2;
  const int b2 = (bx < split) ? bx : bx - split;
  if (p.mr == 4) sgemm_body<4>(p, b2, smem);
  else sgemm_body<7>(p, b2, smem);
}

// ---------------------------------------------------------------------------
// fused: [K6b sgemm (blocks 0..255)] + [codebook argmax (blocks 256..511)]
// ---------------------------------------------------------------------------
__global__ __launch_bounds__(256) void k_gemm_cb(SG p, const float* __restrict__ opv,
                                                 const float* __restrict__ cbv,
                                                 const float* __restrict__ cbsqv,
                                                 unsigned long long* __restrict__ opmaxp) {
  __shared__ __align__(16) char smem[65536];
  const int bx = blockIdx.x;
  if (bx < 256) {
    sgemm_body<7>(p, bx, smem);
    return;
  }
  const int bx2 = bx - 256;
  const int t = threadIdx.x;
  for (int idx = t; idx < 16384; idx += 256) {
    const int x = idx << 2;
    *(float*)(smem + (x ^ (((x >> 7) & 7) << 4))) = opv[idx];
  }
  __syncthreads();
  const int w = t >> 6, l = t & 63;
  const int bxl = 64 * l;
  const int key = ((bxl >> 7) & 7) << 4;
  const int o0 = bxl ^ key, o1 = (bxl + 16) ^ key, o2 = (bxl + 32) ^ key, o3 = (bxl + 48) ^ key;
  unsigned long long bk[16];
#pragma unroll
  for (int m = 0; m < 16; m++) bk[m] = 0ull;
  const int cbase = (bx2 << 5) + (w << 3);
  for (int ci = 0; ci < 8; ci++) {
    const int c = cbase + ci;
    const float4* cr = (const float4*)(cbv + (c << 10));
    const float4 c0 = cr[4 * l], c1 = cr[4 * l + 1], c2 = cr[4 * l + 2], c3 = cr[4 * l + 3];
    float sm[16];
#pragma unroll
    for (int m = 0; m < 16; m++) {
      const char* qp = smem + (m << 12);
      const float4 a0 = *(const float4*)(qp + o0);
      const float4 a1 = *(const float4*)(qp + o1);
      const float4 a2 = *(const float4*)(qp + o2);
      const float4 a3 = *(const float4*)(qp + o3);
      sm[m] = dot4(a0, c0) + dot4(a1, c1) + dot4(a2, c2) + dot4(a3, c3);
    }
#pragma unroll
    for (int off = 32; off > 0; off >>= 1) {
#pragma unroll
      for (int m = 0; m < 16; m++) sm[m] += __shfl_xor(sm[m], off);
    }
    const float cq = cbsqv[c];
#pragma unroll
    for (int m = 0; m < 16; m++) {
      const float sc = fmaf(2.f, sm[m], -cq);
      const unsigned long long k2 = ((unsigned long long)sortable(sc) << 32) | (unsigned)(8192 - c);
      bk[m] = k2 > bk[m] ? k2 : bk[m];
    }
  }
  __syncthreads();
  unsigned long long* red = (unsigned long long*)smem;
  if (l == 0) {
#pragma unroll
    for (int m = 0; m < 16; m++) red[w * 16 + m] = bk[m];
  }
  __syncthreads();
  if (t < 16) {
    unsigned long long b2 = red[t];
    for (int ww = 1; ww < 4; ww++) {
      const unsigned long long v = red[ww * 16 + t];
      b2 = v > b2 ? v : b2;
    }
    opmaxp[bx2 * 16 + t] = b2;
  }
}

// ---------------------------------------------------------------------------
// flash attention, state pass: Q=1/batch, 128 chunks of 16 keys. grid (32,16).
// ---------------------------------------------------------------------------
__global__ __launch_bounds__(256) void k_flash_state(const float* __restrict__ prompt,
                                                     const float* __restrict__ qsv,
                                                     float* __restrict__ accst,
                                                     float* __restrict__ lst) {
  const int b = blockIdx.y;
  const int w = threadIdx.x >> 6, l = threadIdx.x & 63;
  const int chunk = blockIdx.x * 4 + w;  // 0..127
  const float4* qp = (const float4*)(qsv + (b << 10) + 16 * l);
  const float4 q0 = qp[0], q1 = qp[1], q2 = qp[2], q3 = qp[3];
  float4 acc[4];
#pragma unroll
  for (int r = 0; r < 4; r++) acc[r] = make_float4(0.f, 0.f, 0.f, 0.f);
  float lsum = 0.f;
  const float* pbase = prompt + ((b * 2048 + chunk * 16) << 10) + 16 * l;
#pragma unroll 2
  for (int k = 0; k < 16; k++) {
    const float4* pr = (const float4*)(pbase + (k << 10));
    const float4 p0 = pr[0], p1 = pr[1], p2 = pr[2], p3 = pr[3];
    float s = dot4(q0, p0) + dot4(q1, p1) + dot4(q2, p2) + dot4(q3, p3);
#pragma unroll
    for (int off = 32; off > 0; off >>= 1) s += __shfl_xor(s, off);
    const float wgt = __expf(s);
    lsum += wgt;
    AXPY4(acc[0], wgt, p0); AXPY4(acc[1], wgt, p1);
    AXPY4(acc[2], wgt, p2); AXPY4(acc[3], wgt, p3);
  }
  float* ob = accst + ((chunk * 16 + b) << 10) + 16 * l;
#pragma unroll
  for (int r = 0; r < 4; r++) ((float4*)ob)[r] = acc[r];
  if (l == 0) lst[chunk * 16 + b] = lsum;
}

// combine state flash psums: ctx[b][h] = sum_c acc / sum_c l.  grid 256.
__global__ __launch_bounds__(256) void k_cst(const float* __restrict__ accst,
                                             const float* __restrict__ lst,
                                             float* __restrict__ ctx) {
  __shared__ float4 sred[256];
  __shared__ float rinv;
  const int bx = blockIdx.x;
  const int b = bx >> 4, hq = bx & 15;
  const int t = threadIdx.x;
  if (t < 64) {
    float s = 0.f;
    for (int c = t; c < 128; c += 64) s += lst[c * 16 + b];
#pragma unroll
    for (int off = 32; off > 0; off >>= 1) s += __shfl_xor(s, off);
    if (t == 0) rinv = 1.f / s;
  }
  const int h4 = hq * 16 + (t & 15);
  const int cp = t >> 4;
  float4 a = make_float4(0.f, 0.f, 0.f, 0.f);
#pragma unroll
  for (int ci = 0; ci < 8; ci++) {
    const int c = cp * 8 + ci;
    const float4 v = ((const float4*)accst)[((c * 16 + b) << 8) + h4];
    ADD4(a, v);
  }
  sred[t] = a;
  __syncthreads();
  if (t < 16) {
    float4 s = sred[t];
    for (int p2 = 1; p2 < 16; p2++) {
      const float4 v = sred[p2 * 16 + t];
      ADD4(s, v);
    }
    s.x *= rinv; s.y *= rinv; s.z *= rinv; s.w *= rinv;
    ((float4*)ctx)[(b << 8) + hq * 16 + t] = s;
  }
}

// generic psum combine: dst[i] = sum_p src[p*stride + i]
__global__ __launch_bounds__(256) void k_comb(const float* __restrict__ src,
                                              float* __restrict__ dst, int P, int stride) {
  const int i = blockIdx.x * 256 + threadIdx.x;
  float s = 0.f;
  for (int p = 0; p < P; p++) s += src[p * stride + i];
  dst[i] = s;
}

// slot query combine (blocks 0..575) + argmax finish (block 576)
__global__ __launch_bounds__(256) void k_qcomb(const float* __restrict__ qb2,
                                               float* __restrict__ qsl,
                                               const unsigned long long* __restrict__ opmax,
                                               int* __restrict__ opidx) {
  __shared__ unsigned long long red[256];
  const int t = threadIdx.x;
  if (blockIdx.x == 576) {
    const int b = t & 15, part = t >> 4;
    unsigned long long best = 0ull;
    for (int c = part * 16; c < part * 16 + 16; c++) {
      const unsigned long long v = opmax[c * 16 + b];
      best = v > best ? v : best;
    }
    red[t] = best;
    __syncthreads();
    if (t < 16) {
      unsigned long long m = red[t];
      for (int p2 = 1; p2 < 16; p2++) {
        const unsigned long long v = red[p2 * 16 + t];
        m = v > m ? v : m;
      }
      opidx[t] = 8192 - (int)(unsigned)(m & 0xFFFFFFFFull);
    }
    return;
  }
  const int i = blockIdx.x * 256 + t;  // < 147456
  const int h = i & 1023;
  const int r = i >> 10;  // 0..143
  const int b = r / 9, j = r - b * 9;
  float s = 0.f;
  for (int p = 0; p < 16; p++) {
    const float* q = qb2 + p * 25600;
    s += q[(b << 10) + h] + q[((16 + j) << 10) + h];
  }
  qsl[i] = s;
}

// ---------------------------------------------------------------------------
// slot scores: wexp[b][k][9] = exp(q_j . p_k); lpsum per 16-key wave chunk.
// grid (32, 16), wave w handles keys bx*64 + w*16 + [0,16).
// ---------------------------------------------------------------------------
__global__ __launch_bounds__(256) void k_scores(const float* __restrict__ prompt,
                                                const float* __restrict__ qsl,
                                                float* __restrict__ wexp,
                                                float* __restrict__ lpsum) {
  __shared__ __align__(16) char qsm[36864];
  const int b = blockIdx.y;
  const int t = threadIdx.x;
  for (int idx = t; idx < 9216; idx += 256) {
    const int x = idx << 2;
    *(float*)(qsm + (x ^ (((x >> 7) & 7) << 4))) = qsl[b * 9216 + idx];
  }
  __syncthreads();
  const int w = t >> 6, l = t & 63;
  const int bxl = 64 * l;
  const int key = ((bxl >> 7) & 7) << 4;
  const int o0 = bxl ^ key, o1 = (bxl + 16) ^ key, o2 = (bxl + 32) ^ key, o3 = (bxl + 48) ^ key;
  const int k0 = blockIdx.x * 64 + w * 16;
  float lacc = 0.f;
  const float* pbase = prompt + ((b * 2048 + k0) << 10) + 16 * l;
  for (int ki = 0; ki < 16; ki++) {
    const float4* pr = (const float4*)(pbase + (ki << 10));
    const float4 p0 = pr[0], p1 = pr[1], p2 = pr[2], p3 = pr[3];
    float sj[9];
#pragma unroll
    for (int j = 0; j < 9; j++) {
      const char* qp = qsm + (j << 12);
      sj[j] = dot4(*(const float4*)(qp + o0), p0) + dot4(*(const float4*)(qp + o1), p1) +
              dot4(*(const float4*)(qp + o2), p2) + dot4(*(const float4*)(qp + o3), p3);
    }
#pragma unroll
    for (int off = 32; off > 0; off >>= 1) {
#pragma unroll
      for (int j = 0; j < 9; j++) sj[j] += __shfl_xor(sj[j], off);
    }
    float wv = sj[0];
#pragma unroll
    for (int j = 1; j < 9; j++)
      if (l == j) wv = sj[j];
    if (l < 9) {
      const float e = __expf(wv);
      wexp[(b * 2048 + k0 + ki) * 9 + l] = e;
      lacc += e;
    }
  }
  if (l < 9) lpsum[(b * 128 + blockIdx.x * 4 + w) * 9 + l] = lacc;
}

// ---------------------------------------------------------------------------
// slot PV: accp[kc][b][j][h] = sum_{k in kc} wexp[b][k][9] * p[b][k][h]
// grid (32, 16): kc = bx>>1 (16 chunks of 128 keys), hq = bx&1 (512 h).
// wave w covers h = hq*512 + w*128 + lane*2.
// ---------------------------------------------------------------------------
__global__ __launch_bounds__(256) void k_pv(const float* __restrict__ prompt,
                                            const float* __restrict__ wexp,
                                            float* __restrict__ accp) {
  __shared__ float wl[1152];
  const int b = blockIdx.y;
  const int kc = blockIdx.x >> 1;
  const int hq = blockIdx.x & 1;
  const int t = threadIdx.x;
  for (int idx = t; idx < 1152; idx += 256) wl[idx] = wexp[(b * 2048 + kc * 128) * 9 + idx];
  __syncthreads();
  const int w = t >> 6, l = t & 63;
  const int h = hq * 512 + w * 128 + l * 2;
  float2 acc[9];
#pragma unroll
  for (int j = 0; j < 9; j++) acc[j] = make_float2(0.f, 0.f);
  const float* pb = prompt + ((b * 2048 + kc * 128) << 10) + h;
#pragma unroll 4
  for (int k = 0; k < 128; k++) {
    const float2 p2 = *(const float2*)(pb + (k << 10));
    const float* wr = &wl[k * 9];
#pragma unroll
    for (int j = 0; j < 9; j++) {
      acc[j].x = fmaf(wr[j], p2.x, acc[j].x);
      acc[j].y = fmaf(wr[j], p2.y, acc[j].y);
    }
  }
  float* ob = accp + (((kc * 16 + b) * 9) << 10) + h;
#pragma unroll
  for (int j = 0; j < 9; j++) *(float2*)(ob + (j << 10)) = acc[j];
}

// ---------------------------------------------------------------------------
// K7: combine slot PV psums, gates + mask (+global fallback), masked mean
// ---------------------------------------------------------------------------
__global__ __launch_bounds__(256) void k_k7(const float* __restrict__ accp,
                                            const float* __restrict__ lpsum,
                                            const float* __restrict__ qb1,
                                            const float* __restrict__ bgate,
                                            float* __restrict__ ssum) {
  __shared__ float rl[9];
  __shared__ float gpre[25];
  __shared__ int mask_s[9];
  __shared__ float cntInv;
  const int bx = blockIdx.x;
  const int b = bx >> 2;
  const int t = threadIdx.x;
  if (t < 9) {
    float s = 0.f;
    for (int c = 0; c < 128; c++) s += lpsum[(b * 128 + c) * 9 + t];
    rl[t] = 1.f / s;
  }
  if (t >= 32 && t < 57) {
    const int m = t - 32;
    float s = 0.f;
    for (int si = 0; si < 16; si++) s += qb1[(si * 25 + m) * 1025 + 1024];
    gpre[m] = s;
  }
  __syncthreads();
  if (t == 0) {
    const float bg = bgate[0];
    bool any = false;
    for (int bb = 0; bb < 16; bb++)
      for (int j = 0; j < 9; j++)
        if (gpre[bb] + gpre[16 + j] + bg >= 0.f) any = true;
    int cnt = 0;
    if (any) {
      for (int j = 0; j < 9; j++) {
        const int s = (gpre[b] + gpre[16 + j] + bg >= 0.f) ? 1 : 0;
        mask_s[j] = s;
        cnt += s;
      }
    } else {
      float bv = -3.4e38f;
      int bj = 0;
      for (int j = 0; j < 9; j++) {
        const float v = gpre[b] + gpre[16 + j] + bg;
        if (v > bv) { bv = v; bj = j; }
      }
      for (int j = 0; j < 9; j++) mask_s[j] = (j == bj) ? 1 : 0;
      cnt = 1;
    }
    cntInv = 1.f / (float)(cnt > 0 ? cnt : 1);
  }
  __syncthreads();
  const int h = ((bx & 3) << 8) + t;
  float v = 0.f;
  for (int j = 0; j < 9; j++) {
    if (mask_s[j]) {
      float s = 0.f;
      for (int c = 0; c < 16; c++) s += accp[(((c * 16 + b) * 9 + j) << 10) + h];
      v = fmaf(s, rl[j], v);
    }
  }
  ssum[(b << 10) + h] = v * cntInv;
}

// ms = tanh(sum_p k8p + codebook[opidx]); side-writes d_out summary
__global__ __launch_bounds__(256) void k_msc(const float* __restrict__ k8p,
                                             const int* __restrict__ opidx,
                                             const float* __restrict__ cbv,
                                             float* __restrict__ ms,
                                             float* __restrict__ dout, int it) {
  const int i = blockIdx.x * 256 + threadIdx.x;  // < 16384
  const int b = i >> 10, h = i & 1023;
  float s = 0.f;
  for (int p = 0; p < 16; p++) s += k8p[p * 16384 + i];
  const float v = tanhf(s + cbv[(opidx[b] << 10) + h]);
  ms[i] = v;
  dout[(b << 12) + (it << 10) + h] = v;
}

// ---------------------------------------------------------------------------
// K9b: GRU elementwise finish (blocks 0..63) + stop logits (blocks 64..67)
// ---------------------------------------------------------------------------
__global__ __launch_bounds__(256) void k_k9b(const float* __restrict__ gp,
                                             const float* __restrict__ bih,
                                             const float* __restrict__ bhh,
                                             float* __restrict__ state,
                                             const float* __restrict__ stctx,
                                             const float* __restrict__ ms,
                                             const float* __restrict__ Wstop,
                                             const float* __restrict__ bstop,
                                             float* __restrict__ dout, int it) {
  const int bx = blockIdx.x;
  const int t = threadIdx.x;
  if (bx < 64) {
    const int gi = bx * 256 + t;
    const int b = gi >> 10, h = gi & 1023;
    float ir = 0.f, iz = 0.f, inn = 0.f, hr = 0.f, hz = 0.f, hn = 0.f;
    for (int s = 0; s < 8; s++) {
      const float* g = gp + (s * 16 + b) * 6144;
      ir += g[h]; iz += g[1024 + h]; inn += g[2048 + h];
      hr += g[3072 + h]; hz += g[4096 + h]; hn += g[5120 + h];
    }
    ir += bih[h]; iz += bih[1024 + h]; inn += bih[2048 + h];
    hr += bhh[h]; hz += bhh[1024 + h]; hn += bhh[2048 + h];
    const float r = 1.f / (1.f + __expf(-(ir + hr)));
    const float z = 1.f / (1.f + __expf(-(iz + hz)));
    const float n = tanhf(fmaf(r, hn, inn));
    const float hold = state[gi];
    state[gi] = (1.f - z) * n + z * hold;
  } else {
    const int wid = (bx - 64) * 4 + (t >> 6);
    const int l = t & 63;
    float p = 0.f;
    for (int i = 0; i < 16; i++) {
      const int h = l + (i << 6);
      float sc = 0.f;
      for (int s = 0; s < 16; s++) sc += stctx[((s * 16 + wid) << 10) + h];
      p = fmaf(sc, Wstop[h], p);
      p = fmaf(ms[(wid << 10) + h], Wstop[1024 + h], p);
    }
#pragma unroll
    for (int off = 32; off > 0; off >>= 1) p += __shfl_xor(p, off);
    if (l == 0) {
      const float lg = p + bstop[0];
      dout[65536 + wid * 4 + it] = lg;
      dout[65600 + wid * 4 + it] = 1.f / (1.f + __expf(-lg));
    }
  }
}

__global__ void k_k10(float* __restrict__ dout) {
  const int t = threadIdx.x;
  if (t < 16) {
    int cl = 4;
    for (int it = 0; it < 4; it++) {
      if (dout[65536 + t * 4 + it] >= 0.f) { cl = it + 1; break; }
    }
    dout[65664 + t] = (float)cl;
  }
}

// --------------------------- setup kernels ---------------------------------
// row-chunk partial sums with float4 lanes. grid (S, 16).
__global__ __launch_bounds__(256) void k_meanpsum(const float* __restrict__ src,
                                                  float* __restrict__ out, int rpc) {
  const int s = blockIdx.x, b = blockIdx.y, t = threadIdx.x;
  const int R = gridDim.x * rpc;
  const float4* base = (const float4*)src + (size_t)(b * R + s * rpc) * 256 + t;
  float4 acc = make_float4(0.f, 0.f, 0.f, 0.f);
#pragma unroll 4
  for (int r = 0; r < rpc; r++) {
    const float4 v = base[r * 256];
    ADD4(acc, v);
  }
  ((float4*)out)[((s * 16 + b) << 8) + t] = acc;
}

__global__ __launch_bounds__(256) void k_cbsq(const float* __restrict__ cbv,
                                              float* __restrict__ out) {
  const int c = blockIdx.x * 4 + (threadIdx.x >> 6);
  const int l = threadIdx.x & 63;
  const float4* cr = (const float4*)(cbv + (c << 10));
  float s = 0.f;
#pragma unroll
  for (int r = 0; r < 4; r++) {
    const float4 v = cr[4 * l + r];
    s += dot4(v, v);
  }
#pragma unroll
  for (int off = 32; off > 0; off >>= 1) s += __shfl_xor(s, off);
  if (l == 0) out[c] = s;
}

__global__ __launch_bounds__(256) void k_meancat(const float* __restrict__ pmp,
                                                 const float* __restrict__ lmp,
                                                 float* __restrict__ mean) {
  const int gi = blockIdx.x * 256 + threadIdx.x;
  const int b = gi >> 11, k = gi & 2047;
  float v = 0.f;
  if (k < 1024) {
    for (int s = 0; s < 64; s++) v += pmp[((s * 16 + b) << 10) + k];
    v *= (1.f / 2048.f);
  } else {
    const int kk = k - 1024;
    for (int s = 0; s < 16; s++) v += lmp[((s * 16 + b) << 10) + kk];
    v *= (1.f / 512.f);
  }
  mean[b * 2048 + k] = v;
}

__global__ __launch_bounds__(256) void k_s2b(const float* __restrict__ s2p,
                                             float* __restrict__ state) {
  const int gi = blockIdx.x * 256 + threadIdx.x;
  const int b = gi >> 10, h = gi & 1023;
  float s = 0.f;
  for (int si = 0; si < 8; si++) s += s2p[((si * 16 + b) << 10) + h];
  state[gi] = tanhf(s);
}

// ---------------------------------------------------------------------------
// workspace layout (floats); total ~7.33M floats (~29.3 MB)
// ---------------------------------------------------------------------------
static constexpr int F_PMP   = 0;                       // 64*16*1024
static constexpr int F_LMP   = F_PMP   + 1048576;       // 16*16*1024
static constexpr int F_MEAN  = F_LMP   + 262144;        // 16*2048
static constexpr int F_CBSQ  = F_MEAN  + 32768;         // 8192
static constexpr int F_STATE = F_CBSQ  + 8192;          // 16*1024
static constexpr int F_S2P   = F_STATE + 16384;         // 8*16*1024
static constexpr int F_QS1   = F_S2P   + 131072;        // 16*16*1024
static constexpr int F_QS2   = F_QS1   + 262144;        // 16*16*1024
static constexpr int F_QSV   = F_QS2   + 262144;        // 16*1024
static constexpr int F_LST   = F_QSV   + 16384;         // 128*16
static constexpr int F_CTX   = F_LST   + 2048;          // 16*1024
static constexpr int F_STCTX = F_CTX   + 16384;         // 16*16*1024
static constexpr int F_OPP   = F_STCTX + 262144;        // 16*16*1024
static constexpr int F_OPV   = F_OPP   + 262144;        // 16*1024
static constexpr int F_OPMAX = F_OPV   + 16384;         // u64[4096]
static constexpr int F_OPIDX = F_OPMAX + 8192;          // int[16]
static constexpr int F_QB1   = F_OPIDX + 64;            // 16*25*1025
static constexpr int F_QB2   = F_QB1   + 410000;        // 16*25*1024
static constexpr int F_QSL   = F_QB2   + 409600;        // 16*9*1024
static constexpr int F_WEXP  = F_QSL   + 147456;        // 16*2048*9
static constexpr int F_LPS   = F_WEXP  + 294912;        // 16*128*9
static constexpr int F_SSUM  = F_LPS   + 18432;         // 16*1024
static constexpr int F_K8P   = F_SSUM  + 16384;         // 16*16*1024
static constexpr int F_MS    = F_K8P   + 262144;        // 16*1024
static constexpr int F_GP    = F_MS    + 16384;         // 8*16*6144
static constexpr int F_BIG   = F_GP    + 786432;        // max(accst 2.0M, accp 2.25M)
static constexpr int F_END   = F_BIG   + 2359296;

static SG baseSG() {
  SG p;
  p.Bm = nullptr; p.Bg = nullptr; p.a0 = nullptr; p.a1 = nullptr; p.out = nullptr;
  p.M = 16; p.N = 1024; p.Ncore = 1024;
  p.NB = 16; p.kslice = 64; p.ksh = 6;
  p.lda = 1024; p.ldb = 1024; p.ldo = 1024;
  p.MA = 16; p.P = 16; p.amode = A_RAW; p.bt = 0; p.mr = 4;
  p.scale = 1.f;
  return p;
}

extern "C" void kernel_launch(void* const* d_in, const int* in_sizes, int n_in,
                              void* d_out, int out_size, void* d_ws, size_t ws_size,
                              hipStream_t stream) {
  (void)in_sizes; (void)n_in; (void)out_size; (void)ws_size;
  const float* logic  = (const float*)d_in[0];
  const float* prompt = (const float*)d_in[1];
  const float* cbv    = (const float*)d_in[2];
  const float* W_init = (const float*)d_in[3];
  const float* W_pq   = (const float*)d_in[4];
  const float* W_pk   = (const float*)d_in[5];
  const float* W_pv   = (const float*)d_in[6];
  const float* slotq  = (const float*)d_in[7];
  const float* W_sq   = (const float*)d_in[8];
  const float* W_op   = (const float*)d_in[9];
  const float* W_gate = (const float*)d_in[10];
  const float* b_gate = (const float*)d_in[11];
  const float* W_stop = (const float*)d_in[12];
  const float* b_stop = (const float*)d_in[13];
  const float* Wih    = (const float*)d_in[14];
  const float* Whh    = (const float*)d_in[15];
  const float* bih    = (const float*)d_in[16];
  const float* bhh    = (const float*)d_in[17];
  float* out = (float*)d_out;
  float* w = (float*)d_ws;

  const float inv32 = 1.0f / 32.0f;

  // ---- setup ----
  k_meanpsum<<<dim3(64, 16), 256, 0, stream>>>(prompt, w + F_PMP, 32);
  k_meanpsum<<<dim3(16, 16), 256, 0, stream>>>(logic, w + F_LMP, 32);
  k_cbsq<<<2048, 256, 0, stream>>>(cbv, w + F_CBSQ);
  k_meancat<<<128, 256, 0, stream>>>(w + F_PMP, w + F_LMP, w + F_MEAN);
  {
    SG p = baseSG();
    p.a0 = w + F_MEAN; p.Bm = W_init; p.out = w + F_S2P;
    p.kslice = 256; p.ksh = 8; p.lda = 2048; p.NB = 16;  // KSg=8 -> 128 blocks
    k_sgemm<<<128, 256, 0, stream>>>(p);
  }
  k_s2b<<<64, 256, 0, stream>>>(w + F_S2P, w + F_STATE);

  for (int it = 0; it < 4; ++it) {
    // K1a: qs1 = state @ W_pq (16 psums)
    {
      SG p = baseSG();
      p.a0 = w + F_STATE; p.Bm = W_pq; p.out = w + F_QS1;
      k_sgemm<<<256, 256, 0, stream>>>(p);
    }
    // K1b: qs2 = (sum qs1) @ W_pk^T / 32
    {
      SG p = baseSG();
      p.amode = A_PSUM; p.a0 = w + F_QS1; p.Bm = W_pk; p.bt = 1;
      p.out = w + F_QS2; p.scale = inv32;
      k_sgemm<<<256, 256, 0, stream>>>(p);
    }
    // qs2 psums -> qsv
    k_comb<<<64, 256, 0, stream>>>(w + F_QS2, w + F_QSV, 16, 16384);
    // K2: flash state attention (128 chunks)
    k_flash_state<<<dim3(32, 16), 256, 0, stream>>>(prompt, w + F_QSV, w + F_BIG, w + F_LST);
    // combine + normalize -> ctx
    k_cst<<<256, 256, 0, stream>>>(w + F_BIG, w + F_LST, w + F_CTX);
    // K4: stctx = ctx @ W_pv (16 psums)
    {
      SG p = baseSG();
      p.a0 = w + F_CTX; p.Bm = W_pv; p.out = w + F_STCTX;
      k_sgemm<<<256, 256, 0, stream>>>(p);
    }
    // F1: [opp = state_ctx @ W_op] + [qb1 = [state_ctx;slotq] @ [W_sq|W_gate]]
    {
      SG p1 = baseSG();
      p1.amode = A_PSUM; p1.a0 = w + F_STCTX; p1.Bm = W_op; p1.out = w + F_OPP;
      SG p2 = baseSG();
      p2.amode = A_PSRAW; p2.a0 = w + F_STCTX; p2.a1 = slotq;
      p2.Bm = W_sq; p2.Bg = W_gate; p2.M = 25; p2.N = 1025; p2.Ncore = 1024;
      p2.NB = 17; p2.out = w + F_QB1; p2.ldo = 1025; p2.mr = 7;
      k_sgemm2<<<528, 256, 0, stream>>>(p1, p2, 256);
    }
    // opp psums -> opv
    k_comb<<<64, 256, 0, stream>>>(w + F_OPP, w + F_OPV, 16, 16384);
    // F2: [qb2 = (sum qb1) @ W_pk^T / 32] + [codebook argmax]
    {
      SG p = baseSG();
      p.amode = A_PSUM; p.a0 = w + F_QB1; p.MA = 25; p.lda = 1025;
      p.M = 25; p.Bm = W_pk; p.bt = 1; p.out = w + F_QB2; p.scale = inv32; p.mr = 7;
      k_gemm_cb<<<512, 256, 0, stream>>>(p, w + F_OPV, cbv, w + F_CBSQ,
                                         (unsigned long long*)(w + F_OPMAX));
    }
    // qb2 psums -> qsl (blocks 0..575) + argmax finish (block 576)
    k_qcomb<<<577, 256, 0, stream>>>(w + F_QB2, w + F_QSL,
                                     (const unsigned long long*)(w + F_OPMAX),
                                     (int*)(w + F_OPIDX));
    // slot scores + PV
    k_scores<<<dim3(32, 16), 256, 0, stream>>>(prompt, w + F_QSL, w + F_WEXP, w + F_LPS);
    k_pv<<<dim3(32, 16), 256, 0, stream>>>(prompt, w + F_WEXP, w + F_BIG);
    // K7: combine + gates/mask + masked mean -> ssum
    k_k7<<<64, 256, 0, stream>>>(w + F_BIG, w + F_LPS, w + F_QB1, b_gate, w + F_SSUM);
    // K8a: k8p = ssum @ W_pv (16 psums)
    {
      SG p = baseSG();
      p.a0 = w + F_SSUM; p.Bm = W_pv; p.out = w + F_K8P;
      k_sgemm<<<256, 256, 0, stream>>>(p);
    }
    // ms = tanh(op_emb + slot_summary); writes d_out summary
    k_msc<<<64, 256, 0, stream>>>(w + F_K8P, (const int*)(w + F_OPIDX), cbv,
                                  w + F_MS, out, it);
    // K9a: [ms @ Wih] + [state @ Whh] -> gp (8 psums each)
    {
      SG p1 = baseSG();
      p1.a0 = w + F_MS; p1.Bm = Wih; p1.ldb = 3072; p1.N = 3072; p1.Ncore = 3072;
      p1.kslice = 128; p1.ksh = 7; p1.NB = 48;
      p1.out = w + F_GP; p1.ldo = 6144;
      SG p2 = baseSG();
      p2.a0 = w + F_STATE; p2.Bm = Whh; p2.ldb = 3072; p2.N = 3072; p2.Ncore = 3072;
      p2.kslice = 128; p2.ksh = 7; p2.NB = 48;
      p2.out = w + F_GP + 3072; p2.ldo = 6144;
      k_sgemm2<<<768, 256, 0, stream>>>(p1, p2, 384);
    }
    // K9b: GRU finish + stop logits/probs
    k_k9b<<<68, 256, 0, stream>>>(w + F_GP, bih, bhh, w + F_STATE, w + F_STCTX,
                                  w + F_MS, W_stop, b_stop, out, it);
  }
  k_k10<<<1, 64, 0, stream>>>(out);
}

// Round 4
// 1046.964 us; speedup vs baseline: 2.8479x; 1.2706x over previous
//
#include <hip/hip_runtime.h>

// ---------------------------------------------------------------------------
// AutoregressiveMatrixChain on MI355X, fp32.
// R4: structural. Precompute Wqk=W_pq@W_pk^T/32, T1=W_sq@W_pk^T/32 (tiled
// 1024^3 GEMM, one dispatch); wide per-iter GEMM [W_op|T1|W_gate|W_stop];
// fused slot attention (scores+PV, one prompt pass); no more bt-GEMMs.
// ---------------------------------------------------------------------------

#define DINL __device__ __forceinline__

struct SG {
  const float* Bm;   // weight [K][N]
  const float* Bg;   // extra single column for n >= Ncore
  const float* a0;   // A source
  float* out;        // psums [KSg][M][ldo]
  int M, N, Ncore, NB, kslice, ksh, lda, ldb, ldo, mr;
  float scale;
};

DINL float dot4(float4 a, float4 b) {
  return fmaf(a.x, b.x, fmaf(a.y, b.y, fmaf(a.z, b.z, a.w * b.w)));
}
DINL unsigned sortable(float f) {
  unsigned u = __float_as_uint(f);
  return (u & 0x80000000u) ? ~u : (u | 0x80000000u);
}
#define AXPY4(A, W, P) \
  { A.x = fmaf(W, P.x, A.x); A.y = fmaf(W, P.y, A.y); A.z = fmaf(W, P.z, A.z); A.w = fmaf(W, P.w, A.w); }
#define ADD4(A, V) { A.x += V.x; A.y += V.y; A.z += V.z; A.w += V.w; }

// ---------------------------------------------------------------------------
// small GEMM body (A_RAW only): out[ks][m][n] = A[m,kslice]*B[kslice,n]*scale
// ---------------------------------------------------------------------------
template <int MR>
DINL void sgemm_body(const SG p, int bx, float* As) {
  const int t = threadIdx.x;
  const int ks = bx / p.NB, nb = bx % p.NB;
  const int kslice = p.kslice;
  const int kb = ks * kslice;

  const int tot = p.M * kslice;
  for (int idx = t; idx < tot; idx += 256) {
    const int m = idx >> p.ksh;
    const int kl = idx & (kslice - 1);
    As[(m << p.ksh) + kl] = p.a0[m * p.lda + kb + kl];
  }
  __syncthreads();

  const int nl = t & 63, mg = t >> 6;
  const int n = nb * 64 + nl;
  const bool nok = (n < p.N);
  float acc[MR];
#pragma unroll
  for (int i = 0; i < MR; i++) acc[i] = 0.f;

  const bool useg = nok && (n >= p.Ncore);
  const float* Bc = p.Bm + n;
  for (int k4 = 0; k4 < kslice; k4 += 4) {
    float bv[4];
#pragma unroll
    for (int u = 0; u < 4; u++) {
      bv[u] = 0.f;
      if (nok) bv[u] = useg ? p.Bg[kb + k4 + u] : Bc[(kb + k4 + u) * p.ldb];
    }
#pragma unroll
    for (int i = 0; i < MR; i++) {
      const int m = mg + 4 * i;
      if (MR == 4 || m < p.M) {
        const float4 av = *(const float4*)&As[(m << p.ksh) + k4];
        acc[i] = fmaf(av.x, bv[0], acc[i]);
        acc[i] = fmaf(av.y, bv[1], acc[i]);
        acc[i] = fmaf(av.z, bv[2], acc[i]);
        acc[i] = fmaf(av.w, bv[3], acc[i]);
      }
    }
  }

  if (nok) {
#pragma unroll
    for (int i = 0; i < MR; i++) {
      const int m = mg + 4 * i;
      if (MR == 4 || m < p.M) p.out[(ks * p.M + m) * p.ldo + n] = acc[i] * p.scale;
    }
  }
}

__global__ __launch_bounds__(256) void k_sgemm(SG p) {
  __shared__ __align__(16) float As[4352];
  if (p.mr == 4) sgemm_body<4>(p, blockIdx.x, As);
  else sgemm_body<7>(p, blockIdx.x, As);
}

__global__ __launch_bounds__(256) void k_sgemm2(SG p1, SG p2, int split) {
  __shared__ __align__(16) float As[4352];
  const int bx = blockIdx.x;
  const SG& p = (bx < split) ? p1 : p2;
  const int b2 = (bx < split) ? bx : bx - split;
  if (p.mr == 4) sgemm_body<4>(p, b2, As);
  else sgemm_body<7>(p, b2, As);
}

// ---------------------------------------------------------------------------
// setup 1024^3 GEMM: C = A@B^T * scale, two problems in one dispatch.
// 64x64 tiles, BK=32, 256 threads, 4x4 per thread.
// ---------------------------------------------------------------------------
__global__ __launch_bounds__(256) void k_wgemm(const float* __restrict__ A1,
                                               const float* __restrict__ B1,
                                               float* __restrict__ C1,
                                               const float* __restrict__ A2,
                                               const float* __restrict__ B2,
                                               float* __restrict__ C2,
                                               float scale) {
  __shared__ float As[64 * 33], Bs[64 * 33];
  const int which = blockIdx.x >> 8;
  const int bid = blockIdx.x & 255;
  const float* A = which ? A2 : A1;
  const float* B = which ? B2 : B1;
  float* C = which ? C2 : C1;
  const int bi = bid >> 4, bj = bid & 15;
  const int t = threadIdx.x;
  const int lr = t >> 3, lq = t & 7;             // stage: rows lr, lr+32; quad lq
  const int r0 = (t >> 4) << 2, c0 = (t & 15) << 2;
  float acc[4][4];
#pragma unroll
  for (int i = 0; i < 4; i++)
#pragma unroll
    for (int j = 0; j < 4; j++) acc[i][j] = 0.f;

  for (int k0 = 0; k0 < 1024; k0 += 32) {
    __syncthreads();
    {
      const float4 a0 = *(const float4*)&A[(bi * 64 + lr) * 1024 + k0 + lq * 4];
      const float4 a1 = *(const float4*)&A[(bi * 64 + lr + 32) * 1024 + k0 + lq * 4];
      const float4 b0 = *(const float4*)&B[(bj * 64 + lr) * 1024 + k0 + lq * 4];
      const float4 b1 = *(const float4*)&B[(bj * 64 + lr + 32) * 1024 + k0 + lq * 4];
      float* ap = &As[lr * 33 + lq * 4];
      ap[0] = a0.x; ap[1] = a0.y; ap[2] = a0.z; ap[3] = a0.w;
      float* ap2 = &As[(lr + 32) * 33 + lq * 4];
      ap2[0] = a1.x; ap2[1] = a1.y; ap2[2] = a1.z; ap2[3] = a1.w;
      float* bp = &Bs[lr * 33 + lq * 4];
      bp[0] = b0.x; bp[1] = b0.y; bp[2] = b0.z; bp[3] = b0.w;
      float* bp2 = &Bs[(lr + 32) * 33 + lq * 4];
      bp2[0] = b1.x; bp2[1] = b1.y; bp2[2] = b1.z; bp2[3] = b1.w;
    }
    __syncthreads();
#pragma unroll 8
    for (int kk = 0; kk < 32; kk++) {
      float a[4], b[4];
#pragma unroll
      for (int i = 0; i < 4; i++) a[i] = As[(r0 + i) * 33 + kk];
#pragma unroll
      for (int j = 0; j < 4; j++) b[j] = Bs[(c0 + j) * 33 + kk];
#pragma unroll
      for (int i = 0; i < 4; i++)
#pragma unroll
        for (int j = 0; j < 4; j++) acc[i][j] = fmaf(a[i], b[j], acc[i][j]);
    }
  }
#pragma unroll
  for (int i = 0; i < 4; i++) {
    float4 v = make_float4(acc[i][0] * scale, acc[i][1] * scale,
                           acc[i][2] * scale, acc[i][3] * scale);
    *(float4*)&C[(bi * 64 + r0 + i) * 1024 + bj * 64 + c0] = v;
  }
}

// ---------------------------------------------------------------------------
// wide per-iter GEMM: fwP = state_ctx @ [W_op | T1 | W_gate | W_stop_top]
// A = 16 psums of ctx@W_pv; N=2050, ldo=2056; KSg=16, NB=33 -> 528 blocks.
// ---------------------------------------------------------------------------
__global__ __launch_bounds__(256) void k_fw(const float* __restrict__ stp,
                                            const float* __restrict__ Wop,
                                            const float* __restrict__ T1,
                                            const float* __restrict__ Wgate,
                                            const float* __restrict__ Wstop,
                                            float* __restrict__ outp) {
  __shared__ float As[1024];
  const int t = threadIdx.x;
  const int ks = blockIdx.x / 33, nb = blockIdx.x % 33;
  const int kb = ks * 64;
  for (int idx = t; idx < 1024; idx += 256) {
    const int m = idx >> 6, kl = idx & 63;
    float v = 0.f;
    for (int s = 0; s < 16; s++) v += stp[((s * 16 + m) << 10) + kb + kl];
    As[idx] = v;
  }
  __syncthreads();
  const int nl = t & 63, mg = t >> 6;
  const int n = nb * 64 + nl;
  const bool nok = (n < 2050);
  const float* Bc;
  int ldb2;
  if (n < 1024) { Bc = Wop + n; ldb2 = 1024; }
  else if (n < 2048) { Bc = T1 + (n - 1024); ldb2 = 1024; }
  else if (n == 2048) { Bc = Wgate; ldb2 = 1; }
  else { Bc = Wstop; ldb2 = 1; }
  float acc[4] = {0.f, 0.f, 0.f, 0.f};
  for (int k4 = 0; k4 < 64; k4 += 4) {
    float bv[4];
#pragma unroll
    for (int u = 0; u < 4; u++) bv[u] = nok ? Bc[(kb + k4 + u) * ldb2] : 0.f;
#pragma unroll
    for (int i = 0; i < 4; i++) {
      const int m = mg + 4 * i;
      const float4 av = *(const float4*)&As[(m << 6) + k4];
      acc[i] = fmaf(av.x, bv[0], acc[i]);
      acc[i] = fmaf(av.y, bv[1], acc[i]);
      acc[i] = fmaf(av.z, bv[2], acc[i]);
      acc[i] = fmaf(av.w, bv[3], acc[i]);
    }
  }
  if (nok) {
#pragma unroll
    for (int i = 0; i < 4; i++) {
      const int m = mg + 4 * i;
      outp[(ks * 16 + m) * 2056 + n] = acc[i];
    }
  }
}

// ---------------------------------------------------------------------------
// combine FW psums: opv (blocks 0..63), qsl (64..639), scalars (640)
// qsl[b][j][h] = sum_p fwP[p][b][1024+h] + sum_s sqkcP[s][j][h]
// ---------------------------------------------------------------------------
__global__ __launch_bounds__(256) void k_combw(const float* __restrict__ fwP,
                                               const float* __restrict__ sqkcP,
                                               float* __restrict__ opv,
                                               float* __restrict__ qsl,
                                               float* __restrict__ gpre,
                                               float* __restrict__ gc,
                                               float* __restrict__ stopA) {
  const int bx = blockIdx.x;
  const int t = threadIdx.x;
  if (bx < 64) {
    const int i = bx * 256 + t;
    const int b = i >> 10, h = i & 1023;
    float s = 0.f;
    for (int p = 0; p < 16; p++) s += fwP[(p * 16 + b) * 2056 + h];
    opv[i] = s;
  } else if (bx < 640) {
    const int i = (bx - 64) * 256 + t;   // < 147456
    const int h = i & 1023;
    const int r = i >> 10;               // 0..143
    const int b = r / 9, j = r - b * 9;
    float s = 0.f;
    for (int p = 0; p < 16; p++) s += fwP[(p * 16 + b) * 2056 + 1024 + h];
    for (int sp = 0; sp < 4; sp++) s += sqkcP[(sp * 9 + j) * 1025 + h];
    qsl[i] = s;
  } else {
    if (t < 16) {
      float g = 0.f, sa = 0.f;
      for (int p = 0; p < 16; p++) {
        g += fwP[(p * 16 + t) * 2056 + 2048];
        sa += fwP[(p * 16 + t) * 2056 + 2049];
      }
      gpre[t] = g;
      stopA[t] = sa;
    } else if (t < 25) {
      const int j = t - 16;
      float g = 0.f;
      for (int sp = 0; sp < 4; sp++) g += sqkcP[(sp * 9 + j) * 1025 + 1024];
      gc[j] = g;
    }
  }
}

// ---------------------------------------------------------------------------
// codebook argmax: scores[b][c] = 2*opv[b].cb[c] - |cb[c]|^2, packed-u64 max.
// grid 256, 32 codes per block.
// ---------------------------------------------------------------------------
__global__ __launch_bounds__(256) void k_cb(const float* __restrict__ opv,
                                            const float* __restrict__ cbv,
                                            const float* __restrict__ cbsqv,
                                            unsigned long long* __restrict__ opmaxp) {
  __shared__ __align__(16) char smem[65536];
  const int bx2 = blockIdx.x;
  const int t = threadIdx.x;
  for (int idx = t; idx < 16384; idx += 256) {
    const int x = idx << 2;
    *(float*)(smem + (x ^ (((x >> 7) & 7) << 4))) = opv[idx];
  }
  __syncthreads();
  const int w = t >> 6, l = t & 63;
  const int bxl = 64 * l;
  const int key = ((bxl >> 7) & 7) << 4;
  const int o0 = bxl ^ key, o1 = (bxl + 16) ^ key, o2 = (bxl + 32) ^ key, o3 = (bxl + 48) ^ key;
  unsigned long long bk[16];
#pragma unroll
  for (int m = 0; m < 16; m++) bk[m] = 0ull;
  const int cbase = (bx2 << 5) + (w << 3);
  for (int ci = 0; ci < 8; ci++) {
    const int c = cbase + ci;
    const float4* cr = (const float4*)(cbv + (c << 10));
    const float4 c0 = cr[4 * l], c1 = cr[4 * l + 1], c2 = cr[4 * l + 2], c3 = cr[4 * l + 3];
    float sm[16];
#pragma unroll
    for (int m = 0; m < 16; m++) {
      const char* qp = smem + (m << 12);
      const float4 a0 = *(const float4*)(qp + o0);
      const float4 a1 = *(const float4*)(qp + o1);
      const float4 a2 = *(const float4*)(qp + o2);
      const float4 a3 = *(const float4*)(qp + o3);
      sm[m] = dot4(a0, c0) + dot4(a1, c1) + dot4(a2, c2) + dot4(a3, c3);
    }
#pragma unroll
    for (int off = 32; off > 0; off >>= 1) {
#pragma unroll
      for (int m = 0; m < 16; m++) sm[m] += __shfl_xor(sm[m], off);
    }
    const float cq = cbsqv[c];
#pragma unroll
    for (int m = 0; m < 16; m++) {
      const float sc = fmaf(2.f, sm[m], -cq);
      const unsigned long long k2 = ((unsigned long long)sortable(sc) << 32) | (unsigned)(8192 - c);
      bk[m] = k2 > bk[m] ? k2 : bk[m];
    }
  }
  __syncthreads();
  unsigned long long* red = (unsigned long long*)smem;
  if (l == 0) {
#pragma unroll
    for (int m = 0; m < 16; m++) red[w * 16 + m] = bk[m];
  }
  __syncthreads();
  if (t < 16) {
    unsigned long long b2 = red[t];
    for (int ww = 1; ww < 4; ww++) {
      const unsigned long long v = red[ww * 16 + t];
      b2 = v > b2 ? v : b2;
    }
    opmaxp[bx2 * 16 + t] = b2;
  }
}

// ---------------------------------------------------------------------------
// flash attention, state pass: Q=1/batch, 128 chunks of 16 keys. grid (32,16).
// ---------------------------------------------------------------------------
__global__ __launch_bounds__(256) void k_flash_state(const float* __restrict__ prompt,
                                                     const float* __restrict__ qsv,
                                                     float* __restrict__ accst,
                                                     float* __restrict__ lst) {
  const int b = blockIdx.y;
  const int w = threadIdx.x >> 6, l = threadIdx.x & 63;
  const int chunk = blockIdx.x * 4 + w;  // 0..127
  const float4* qp = (const float4*)(qsv + (b << 10) + 16 * l);
  const float4 q0 = qp[0], q1 = qp[1], q2 = qp[2], q3 = qp[3];
  float4 acc[4];
#pragma unroll
  for (int r = 0; r < 4; r++) acc[r] = make_float4(0.f, 0.f, 0.f, 0.f);
  float lsum = 0.f;
  const float* pbase = prompt + ((b * 2048 + chunk * 16) << 10) + 16 * l;
#pragma unroll 2
  for (int k = 0; k < 16; k++) {
    const float4* pr = (const float4*)(pbase + (k << 10));
    const float4 p0 = pr[0], p1 = pr[1], p2 = pr[2], p3 = pr[3];
    float s = dot4(q0, p0) + dot4(q1, p1) + dot4(q2, p2) + dot4(q3, p3);
#pragma unroll
    for (int off = 32; off > 0; off >>= 1) s += __shfl_xor(s, off);
    const float wgt = __expf(s);
    lsum += wgt;
    AXPY4(acc[0], wgt, p0); AXPY4(acc[1], wgt, p1);
    AXPY4(acc[2], wgt, p2); AXPY4(acc[3], wgt, p3);
  }
  float* ob = accst + ((chunk * 16 + b) << 10) + 16 * l;
#pragma unroll
  for (int r = 0; r < 4; r++) ((float4*)ob)[r] = acc[r];
  if (l == 0) lst[chunk * 16 + b] = lsum;
}

// combine state flash psums: ctx[b][h] = sum_c acc / sum_c l.  grid 256.
__global__ __launch_bounds__(256) void k_cst(const float* __restrict__ accst,
                                             const float* __restrict__ lst,
                                             float* __restrict__ ctx) {
  __shared__ float4 sred[256];
  __shared__ float rinv;
  const int bx = blockIdx.x;
  const int b = bx >> 4, hq = bx & 15;
  const int t = threadIdx.x;
  if (t < 64) {
    float s = 0.f;
    for (int c = t; c < 128; c += 64) s += lst[c * 16 + b];
#pragma unroll
    for (int off = 32; off > 0; off >>= 1) s += __shfl_xor(s, off);
    if (t == 0) rinv = 1.f / s;
  }
  const int h4 = hq * 16 + (t & 15);
  const int cp = t >> 4;
  float4 a = make_float4(0.f, 0.f, 0.f, 0.f);
#pragma unroll
  for (int ci = 0; ci < 8; ci++) {
    const int c = cp * 8 + ci;
    const float4 v = ((const float4*)accst)[((c * 16 + b) << 8) + h4];
    ADD4(a, v);
  }
  sred[t] = a;
  __syncthreads();
  if (t < 16) {
    float4 s = sred[t];
    for (int p2 = 1; p2 < 16; p2++) {
      const float4 v = sred[p2 * 16 + t];
      ADD4(s, v);
    }
    s.x *= rinv; s.y *= rinv; s.z *= rinv; s.w *= rinv;
    ((float4*)ctx)[(b << 8) + hq * 16 + t] = s;
  }
}

// generic psum combine: dst[i] = sum_p src[p*stride + i]
__global__ __launch_bounds__(256) void k_comb(const float* __restrict__ src,
                                              float* __restrict__ dst, int P, int stride) {
  const int i = blockIdx.x * 256 + threadIdx.x;
  float s = 0.f;
  for (int p = 0; p < P; p++) s += src[p * stride + i];
  dst[i] = s;
}

// ---------------------------------------------------------------------------
// fused slot attention: 64 keys/block, grid (32,16).
// phase 1: scores+exp into LDS; phase 2: PV over the same keys (L2/L3-hot).
// ---------------------------------------------------------------------------
__global__ __launch_bounds__(256) void k_slotattn(const float* __restrict__ prompt,
                                                  const float* __restrict__ qsl,
                                                  float* __restrict__ accp,
                                                  float* __restrict__ lpsum) {
  __shared__ __align__(16) char qsm[36864];
  __shared__ float wl[64 * 9];
  __shared__ float lred[4 * 9];
  const int b = blockIdx.y, kc = blockIdx.x;
  const int t = threadIdx.x;
  for (int idx = t; idx < 9216; idx += 256) {
    const int x = idx << 2;
    *(float*)(qsm + (x ^ (((x >> 7) & 7) << 4))) = qsl[b * 9216 + idx];
  }
  __syncthreads();
  const int w = t >> 6, l = t & 63;
  const int bxl = 64 * l;
  const int key = ((bxl >> 7) & 7) << 4;
  const int o0 = bxl ^ key, o1 = (bxl + 16) ^ key, o2 = (bxl + 32) ^ key, o3 = (bxl + 48) ^ key;
  const int k0 = kc * 64 + w * 16;
  float lacc = 0.f;
  const float* pbase = prompt + ((b * 2048 + k0) << 10) + 16 * l;
  for (int ki = 0; ki < 16; ki++) {
    const float4* pr = (const float4*)(pbase + (ki << 10));
    const float4 p0 = pr[0], p1 = pr[1], p2 = pr[2], p3 = pr[3];
    float sj[9];
#pragma unroll
    for (int j = 0; j < 9; j++) {
      const char* qp = qsm + (j << 12);
      sj[j] = dot4(*(const float4*)(qp + o0), p0) + dot4(*(const float4*)(qp + o1), p1) +
              dot4(*(const float4*)(qp + o2), p2) + dot4(*(const float4*)(qp + o3), p3);
    }
#pragma unroll
    for (int off = 32; off > 0; off >>= 1) {
#pragma unroll
      for (int j = 0; j < 9; j++) sj[j] += __shfl_xor(sj[j], off);
    }
    float wv = sj[0];
#pragma unroll
    for (int j = 1; j < 9; j++)
      if (l == j) wv = sj[j];
    if (l < 9) {
      const float e = __expf(wv);
      wl[(w * 16 + ki) * 9 + l] = e;
      lacc += e;
    }
  }
  if (l < 9) lred[w * 9 + l] = lacc;
  __syncthreads();
  if (t < 9) lpsum[(b * 32 + kc) * 9 + t] = lred[t] + lred[9 + t] + lred[18 + t] + lred[27 + t];
  // phase 2: PV, wave w covers h-slice [w*256, w*256+256)
  const int h4 = (w << 8) + (l << 2);
  float4 acc[9];
#pragma unroll
  for (int j = 0; j < 9; j++) acc[j] = make_float4(0.f, 0.f, 0.f, 0.f);
  const float* pb2 = prompt + ((b * 2048 + kc * 64) << 10) + h4;
#pragma unroll 2
  for (int k = 0; k < 64; k++) {
    const float4 pv = *(const float4*)(pb2 + (k << 10));
    const float* wr = &wl[k * 9];
#pragma unroll
    for (int j = 0; j < 9; j++) AXPY4(acc[j], wr[j], pv);
  }
  float* ob = accp + (((kc * 16 + b) * 9) << 10) + h4;
#pragma unroll
  for (int j = 0; j < 9; j++) *(float4*)(ob + (j << 10)) = acc[j];
}

// ---------------------------------------------------------------------------
// K7: combine slot PV psums + gates/mask/fallback + masked mean (blocks 0..63);
// block 64: codebook argmax finish -> opidx.
// ---------------------------------------------------------------------------
__global__ __launch_bounds__(256) void k_k7(const float* __restrict__ accp,
                                            const float* __restrict__ lpsum,
                                            const float* __restrict__ gpre_g,
                                            const float* __restrict__ gc_g,
                                            const float* __restrict__ bgate,
                                            const unsigned long long* __restrict__ opmax,
                                            int* __restrict__ opidx,
                                            float* __restrict__ ssum) {
  __shared__ unsigned long long red[256];
  __shared__ float rl[9];
  __shared__ float gpre[16];
  __shared__ float gcs[9];
  __shared__ int mask_s[9];
  __shared__ float cntInv;
  const int bx = blockIdx.x;
  const int t = threadIdx.x;
  if (bx == 64) {
    const int b = t & 15, part = t >> 4;
    unsigned long long best = 0ull;
    for (int c = part * 16; c < part * 16 + 16; c++) {
      const unsigned long long v = opmax[c * 16 + b];
      best = v > best ? v : best;
    }
    red[t] = best;
    __syncthreads();
    if (t < 16) {
      unsigned long long m = red[t];
      for (int p2 = 1; p2 < 16; p2++) {
        const unsigned long long v = red[p2 * 16 + t];
        m = v > m ? v : m;
      }
      opidx[t] = 8192 - (int)(unsigned)(m & 0xFFFFFFFFull);
    }
    return;
  }
  const int b = bx >> 2;
  if (t < 9) {
    float s = 0.f;
    for (int c = 0; c < 32; c++) s += lpsum[(b * 32 + c) * 9 + t];
    rl[t] = 1.f / s;
  }
  if (t >= 32 && t < 48) gpre[t - 32] = gpre_g[t - 32];
  if (t >= 48 && t < 57) gcs[t - 48] = gc_g[t - 48];
  __syncthreads();
  if (t == 0) {
    const float bg = bgate[0];
    bool any = false;
    for (int bb = 0; bb < 16; bb++)
      for (int j = 0; j < 9; j++)
        if (gpre[bb] + gcs[j] + bg >= 0.f) any = true;
    int cnt = 0;
    if (any) {
      for (int j = 0; j < 9; j++) {
        const int s = (gpre[b] + gcs[j] + bg >= 0.f) ? 1 : 0;
        mask_s[j] = s;
        cnt += s;
      }
    } else {
      float bv = -3.4e38f;
      int bj = 0;
      for (int j = 0; j < 9; j++) {
        const float v = gpre[b] + gcs[j] + bg;
        if (v > bv) { bv = v; bj = j; }
      }
      for (int j = 0; j < 9; j++) mask_s[j] = (j == bj) ? 1 : 0;
      cnt = 1;
    }
    cntInv = 1.f / (float)(cnt > 0 ? cnt : 1);
  }
  __syncthreads();
  const int h = ((bx & 3) << 8) + t;
  float v = 0.f;
  for (int j = 0; j < 9; j++) {
    if (mask_s[j]) {
      float s = 0.f;
      for (int c = 0; c < 32; c++) s += accp[(((c * 16 + b) * 9 + j) << 10) + h];
      v = fmaf(s, rl[j], v);
    }
  }
  ssum[(b << 10) + h] = v * cntInv;
}

// ms = tanh(sum_p k8p + codebook[opidx]); side-writes d_out summary
__global__ __launch_bounds__(256) void k_msc(const float* __restrict__ k8p,
                                             const int* __restrict__ opidx,
                                             const float* __restrict__ cbv,
                                             float* __restrict__ ms,
                                             float* __restrict__ dout, int it) {
  const int i = blockIdx.x * 256 + threadIdx.x;  // < 16384
  const int b = i >> 10, h = i & 1023;
  float s = 0.f;
  for (int p = 0; p < 16; p++) s += k8p[p * 16384 + i];
  const float v = tanhf(s + cbv[(opidx[b] << 10) + h]);
  ms[i] = v;
  dout[(b << 12) + (it << 10) + h] = v;
}

// ---------------------------------------------------------------------------
// K9b: GRU elementwise finish (blocks 0..63) + stop logits (blocks 64..67)
// ---------------------------------------------------------------------------
__global__ __launch_bounds__(256) void k_k9b(const float* __restrict__ gp,
                                             const float* __restrict__ bih,
                                             const float* __restrict__ bhh,
                                             float* __restrict__ state,
                                             const float* __restrict__ stopA,
                                             const float* __restrict__ ms,
                                             const float* __restrict__ Wstop,
                                             const float* __restrict__ bstop,
                                             float* __restrict__ dout, int it) {
  const int bx = blockIdx.x;
  const int t = threadIdx.x;
  if (bx < 64) {
    const int gi = bx * 256 + t;
    const int b = gi >> 10, h = gi & 1023;
    float ir = 0.f, iz = 0.f, inn = 0.f, hr = 0.f, hz = 0.f, hn = 0.f;
    for (int s = 0; s < 8; s++) {
      const float* g = gp + (s * 16 + b) * 6144;
      ir += g[h]; iz += g[1024 + h]; inn += g[2048 + h];
      hr += g[3072 + h]; hz += g[4096 + h]; hn += g[5120 + h];
    }
    ir += bih[h]; iz += bih[1024 + h]; inn += bih[2048 + h];
    hr += bhh[h]; hz += bhh[1024 + h]; hn += bhh[2048 + h];
    const float r = 1.f / (1.f + __expf(-(ir + hr)));
    const float z = 1.f / (1.f + __expf(-(iz + hz)));
    const float n = tanhf(fmaf(r, hn, inn));
    const float hold = state[gi];
    state[gi] = (1.f - z) * n + z * hold;
  } else {
    const int wid = (bx - 64) * 4 + (t >> 6);
    const int l = t & 63;
    float p = 0.f;
    for (int i = 0; i < 16; i++) {
      const int h = l + (i << 6);
      p = fmaf(ms[(wid << 10) + h], Wstop[1024 + h], p);
    }
#pragma unroll
    for (int off = 32; off > 0; off >>= 1) p += __shfl_xor(p, off);
    if (l == 0) {
      const float lg = p + stopA[wid] + bstop[0];
      dout[65536 + wid * 4 + it] = lg;
      dout[65600 + wid * 4 + it] = 1.f / (1.f + __expf(-lg));
    }
  }
}

__global__ void k_k10(float* __restrict__ dout) {
  const int t = threadIdx.x;
  if (t < 16) {
    int cl = 4;
    for (int it = 0; it < 4; it++) {
      if (dout[65536 + t * 4 + it] >= 0.f) { cl = it + 1; break; }
    }
    dout[65664 + t] = (float)cl;
  }
}

// --------------------------- setup kernels ---------------------------------
__global__ __launch_bounds__(256) void k_meanpsum(const float* __restrict__ src,
                                                  float* __restrict__ out, int rpc) {
  const int s = blockIdx.x, b = blockIdx.y, t = threadIdx.x;
  const int R = gridDim.x * rpc;
  const float4* base = (const float4*)src + (size_t)(b * R + s * rpc) * 256 + t;
  float4 acc = make_float4(0.f, 0.f, 0.f, 0.f);
#pragma unroll 4
  for (int r = 0; r < rpc; r++) {
    const float4 v = base[r * 256];
    ADD4(acc, v);
  }
  ((float4*)out)[((s * 16 + b) << 8) + t] = acc;
}

__global__ __launch_bounds__(256) void k_cbsq(const float* __restrict__ cbv,
                                              float* __restrict__ out) {
  const int c = blockIdx.x * 4 + (threadIdx.x >> 6);
  const int l = threadIdx.x & 63;
  const float4* cr = (const float4*)(cbv + (c << 10));
  float s = 0.f;
#pragma unroll
  for (int r = 0; r < 4; r++) {
    const float4 v = cr[4 * l + r];
    s += dot4(v, v);
  }
#pragma unroll
  for (int off = 32; off > 0; off >>= 1) s += __shfl_xor(s, off);
  if (l == 0) out[c] = s;
}

__global__ __launch_bounds__(256) void k_meancat(const float* __restrict__ pmp,
                                                 const float* __restrict__ lmp,
                                                 float* __restrict__ mean) {
  const int gi = blockIdx.x * 256 + threadIdx.x;
  const int b = gi >> 11, k = gi & 2047;
  float v = 0.f;
  if (k < 1024) {
    for (int s = 0; s < 64; s++) v += pmp[((s * 16 + b) << 10) + k];
    v *= (1.f / 2048.f);
  } else {
    const int kk = k - 1024;
    for (int s = 0; s < 16; s++) v += lmp[((s * 16 + b) << 10) + kk];
    v *= (1.f / 512.f);
  }
  mean[b * 2048 + k] = v;
}

__global__ __launch_bounds__(256) void k_s2b(const float* __restrict__ s2p,
                                             float* __restrict__ state) {
  const int gi = blockIdx.x * 256 + threadIdx.x;
  const int b = gi >> 10, h = gi & 1023;
  float s = 0.f;
  for (int si = 0; si < 8; si++) s += s2p[((si * 16 + b) << 10) + h];
  state[gi] = tanhf(s);
}

// ---------------------------------------------------------------------------
// workspace layout (floats); total ~10.70M floats (~42.8 MB)
// ---------------------------------------------------------------------------
static constexpr int F_PMP   = 0;                    // 64*16*1024
static constexpr int F_LMP   = F_PMP   + 1048576;    // 16*16*1024
static constexpr int F_MEAN  = F_LMP   + 262144;     // 16*2048
static constexpr int F_CBSQ  = F_MEAN  + 32768;      // 8192
static constexpr int F_STATE = F_CBSQ  + 8192;       // 16*1024
static constexpr int F_S2P   = F_STATE + 16384;      // 8*16*1024
static constexpr int F_WQK   = F_S2P   + 131072;     // 1024*1024
static constexpr int F_T1    = F_WQK   + 1048576;    // 1024*1024
static constexpr int F_SQKCP = F_T1    + 1048576;    // 4*9*1025 = 36900 (pad)
static constexpr int F_QS1   = F_SQKCP + 36928;      // 16*16*1024
static constexpr int F_QSV   = F_QS1   + 262144;     // 16*1024
static constexpr int F_LST   = F_QSV   + 16384;      // 128*16
static constexpr int F_CTX   = F_LST   + 2048;       // 16*1024
static constexpr int F_STCTX = F_CTX   + 16384;      // 16*16*1024
static constexpr int F_FWP   = F_STCTX + 262144;     // 16*16*2056
static constexpr int F_OPV   = F_FWP   + 526336;     // 16*1024
static constexpr int F_OPMAX = F_OPV   + 16384;      // u64[4096]
static constexpr int F_OPIDX = F_OPMAX + 8192;       // int[16]
static constexpr int F_GPRE  = F_OPIDX + 64;         // 16
static constexpr int F_GC    = F_GPRE  + 64;         // 9
static constexpr int F_STOPA = F_GC    + 64;         // 16
static constexpr int F_QSL   = F_STOPA + 64;         // 16*9*1024
static constexpr int F_LPS   = F_QSL   + 147456;     // 16*32*9
static constexpr int F_SSUM  = F_LPS   + 4608;       // 16*1024
static constexpr int F_K8P   = F_SSUM  + 16384;      // 16*16*1024
static constexpr int F_MS    = F_K8P   + 262144;     // 16*1024
static constexpr int F_GP    = F_MS    + 16384;      // 8*16*6144
static constexpr int F_BIG   = F_GP    + 786432;     // max(accst 2.0M, accp 4.7M)
static constexpr int F_END   = F_BIG   + 4718592;

static SG baseSG() {
  SG p;
  p.Bm = nullptr; p.Bg = nullptr; p.a0 = nullptr; p.out = nullptr;
  p.M = 16; p.N = 1024; p.Ncore = 1024;
  p.NB = 16; p.kslice = 64; p.ksh = 6;
  p.lda = 1024; p.ldb = 1024; p.ldo = 1024;
  p.mr = 4; p.scale = 1.f;
  return p;
}

extern "C" void kernel_launch(void* const* d_in, const int* in_sizes, int n_in,
                              void* d_out, int out_size, void* d_ws, size_t ws_size,
                              hipStream_t stream) {
  (void)in_sizes; (void)n_in; (void)out_size; (void)ws_size;
  const float* logic  = (const float*)d_in[0];
  const float* prompt = (const float*)d_in[1];
  const float* cbv    = (const float*)d_in[2];
  const float* W_init = (const float*)d_in[3];
  const float* W_pq   = (const float*)d_in[4];
  const float* W_pk   = (const float*)d_in[5];
  const float* W_pv   = (const float*)d_in[6];
  const float* slotq  = (const float*)d_in[7];
  const float* W_sq   = (const float*)d_in[8];
  const float* W_op   = (const float*)d_in[9];
  const float* W_gate = (const float*)d_in[10];
  const float* b_gate = (const float*)d_in[11];
  const float* W_stop = (const float*)d_in[12];
  const float* b_stop = (const float*)d_in[13];
  const float* Wih    = (const float*)d_in[14];
  const float* Whh    = (const float*)d_in[15];
  const float* bih    = (const float*)d_in[16];
  const float* bhh    = (const float*)d_in[17];
  float* out = (float*)d_out;
  float* w = (float*)d_ws;

  const float inv32 = 1.0f / 32.0f;

  // ---- setup ----
  k_meanpsum<<<dim3(64, 16), 256, 0, stream>>>(prompt, w + F_PMP, 32);
  k_meanpsum<<<dim3(16, 16), 256, 0, stream>>>(logic, w + F_LMP, 32);
  k_cbsq<<<2048, 256, 0, stream>>>(cbv, w + F_CBSQ);
  k_meancat<<<128, 256, 0, stream>>>(w + F_PMP, w + F_LMP, w + F_MEAN);
  {
    SG p = baseSG();
    p.a0 = w + F_MEAN; p.Bm = W_init; p.out = w + F_S2P;
    p.kslice = 256; p.ksh = 8; p.lda = 2048; p.NB = 16;  // KSg=8 -> 128 blocks
    k_sgemm<<<128, 256, 0, stream>>>(p);
  }
  k_s2b<<<64, 256, 0, stream>>>(w + F_S2P, w + F_STATE);
  // Wqk = W_pq@W_pk^T/32 ; T1 = W_sq@W_pk^T/32 (one dispatch)
  k_wgemm<<<512, 256, 0, stream>>>(W_pq, W_pk, w + F_WQK, W_sq, W_pk, w + F_T1, inv32);
  // sqkcP = slotq @ [T1 | W_gate]  (4 psums, M=9, N=1025)
  {
    SG p = baseSG();
    p.a0 = slotq; p.Bm = w + F_T1; p.Bg = W_gate;
    p.M = 9; p.N = 1025; p.Ncore = 1024; p.NB = 17;
    p.kslice = 256; p.ksh = 8; p.out = w + F_SQKCP; p.ldo = 1025; p.mr = 7;
    k_sgemm<<<68, 256, 0, stream>>>(p);
  }

  for (int it = 0; it < 4; ++it) {
    // qsvP = state @ Wqk (16 psums)
    {
      SG p = baseSG();
      p.a0 = w + F_STATE; p.Bm = w + F_WQK; p.out = w + F_QS1;
      k_sgemm<<<256, 256, 0, stream>>>(p);
    }
    k_comb<<<64, 256, 0, stream>>>(w + F_QS1, w + F_QSV, 16, 16384);
    // flash state attention (128 chunks)
    k_flash_state<<<dim3(32, 16), 256, 0, stream>>>(prompt, w + F_QSV, w + F_BIG, w + F_LST);
    k_cst<<<256, 256, 0, stream>>>(w + F_BIG, w + F_LST, w + F_CTX);
    // stctxP = ctx @ W_pv (16 psums) -> state_ctx
    {
      SG p = baseSG();
      p.a0 = w + F_CTX; p.Bm = W_pv; p.out = w + F_STCTX;
      k_sgemm<<<256, 256, 0, stream>>>(p);
    }
    // wide GEMM: fwP = state_ctx @ [W_op | T1 | W_gate | W_stop_top]
    k_fw<<<528, 256, 0, stream>>>(w + F_STCTX, W_op, w + F_T1, W_gate, W_stop, w + F_FWP);
    // combine: opv, qsl, gate/stop scalars
    k_combw<<<641, 256, 0, stream>>>(w + F_FWP, w + F_SQKCP, w + F_OPV, w + F_QSL,
                                     w + F_GPRE, w + F_GC, w + F_STOPA);
    // codebook argmax partials
    k_cb<<<256, 256, 0, stream>>>(w + F_OPV, cbv, w + F_CBSQ,
                                  (unsigned long long*)(w + F_OPMAX));
    // fused slot attention (scores + PV)
    k_slotattn<<<dim3(32, 16), 256, 0, stream>>>(prompt, w + F_QSL, w + F_BIG, w + F_LPS);
    // K7: mask + masked mean (+ argmax finish in block 64)
    k_k7<<<65, 256, 0, stream>>>(w + F_BIG, w + F_LPS, w + F_GPRE, w + F_GC, b_gate,
                                 (const unsigned long long*)(w + F_OPMAX),
                                 (int*)(w + F_OPIDX), w + F_SSUM);
    // k8pP = ssum @ W_pv (16 psums)
    {
      SG p = baseSG();
      p.a0 = w + F_SSUM; p.Bm = W_pv; p.out = w + F_K8P;
      k_sgemm<<<256, 256, 0, stream>>>(p);
    }
    // ms = tanh(op_emb + slot_summary); writes d_out summary
    k_msc<<<64, 256, 0, stream>>>(w + F_K8P, (const int*)(w + F_OPIDX), cbv,
                                  w + F_MS, out, it);
    // GRU: [ms @ Wih] + [state @ Whh] -> gp (8 psums each)
    {
      SG p1 = baseSG();
      p1.a0 = w + F_MS; p1.Bm = Wih; p1.ldb = 3072; p1.N = 3072; p1.Ncore = 3072;
      p1.kslice = 128; p1.ksh = 7; p1.NB = 48;
      p1.out = w + F_GP; p1.ldo = 6144;
      SG p2 = baseSG();
      p2.a0 = w + F_STATE; p2.Bm = Whh; p2.ldb = 3072; p2.N = 3072; p2.Ncore = 3072;
      p2.kslice = 128; p2.ksh = 7; p2.NB = 48;
      p2.out = w + F_GP + 3072; p2.ldo = 6144;
      k_sgemm2<<<768, 256, 0, stream>>>(p1, p2, 384);
    }
    // GRU finish + stop logits/probs
    k_k9b<<<68, 256, 0, stream>>>(w + F_GP, bih, bhh, w + F_STATE, w + F_STOPA,
                                  w + F_MS, W_stop, b_stop, out, it);
  }
  k_k10<<<1, 64, 0, stream>>>(out);
}